// Round 4
// baseline (1239.342 us; speedup 1.0000x reference)
//
#include <hip/hip_runtime.h>

#define N_NODES 100000
#define N_EDGES 1600000
#define IN_F   128
#define HID_F  64
#define Z_F    32
#define NBUK   782          // ceil(100000/128) buckets of 128 dst nodes
#define BCAP   3072         // bucket capacity (mean 2046, sigma ~45 -> +22 sigma)
#define P1T    2048         // edges per phase1 block
#define P1_BLOCKS ((N_EDGES + P1T - 1) / P1T)   // 782

typedef unsigned int uint32;

__device__ __forceinline__ unsigned short f2bf(float f) {
    unsigned u = __float_as_uint(f);
    u = (u + 0x7FFF + ((u >> 16) & 1)) >> 16;   // RNE
    return (unsigned short)u;
}
__device__ __forceinline__ float bflo(uint32 u) { return __uint_as_float(u << 16); }
__device__ __forceinline__ float bfhi(uint32 u) { return __uint_as_float(u & 0xFFFF0000u); }

// ---------------- phase 1: bucket partition with LDS-staged chunked writeback ----
// pairs entry: src (17 bits) | local_dst (7 bits) << 17, grouped by bucket (unsorted within).
__global__ __launch_bounds__(256) void phase1_kernel(const int* __restrict__ ei,
                                                     int* __restrict__ gcur,
                                                     uint32* __restrict__ pairs) {
    __shared__ int hist[NBUK];
    __shared__ int lbase[NBUK];
    __shared__ int gbase[NBUK];
    __shared__ int lcur[NBUK];
    __shared__ uint32 stage[P1T];
    __shared__ unsigned short sbid[P1T];
    __shared__ int part[256];
    int tid = threadIdx.x;
    int e0 = blockIdx.x * P1T;
    int ecnt = N_EDGES - e0; if (ecnt > P1T) ecnt = P1T;
    for (int b = tid; b < NBUK; b += 256) { hist[b] = 0; lcur[b] = 0; }
    __syncthreads();
    for (int k = tid; k < ecnt; k += 256)
        atomicAdd(&hist[ei[N_EDGES + e0 + k] >> 7], 1);
    __syncthreads();
    // exclusive scan of hist[0..NBUK): serial-4 per thread + 256-wide block scan
    int t4 = tid * 4;
    int l0 = 0, l1 = 0, l2 = 0, l3 = 0, s = 0;
    if (t4 + 0 < NBUK) { l0 = hist[t4 + 0]; s += l0; }
    if (t4 + 1 < NBUK) { l1 = hist[t4 + 1]; s += l1; }
    if (t4 + 2 < NBUK) { l2 = hist[t4 + 2]; s += l2; }
    if (t4 + 3 < NBUK) { l3 = hist[t4 + 3]; s += l3; }
    part[tid] = s;
    __syncthreads();
    for (int off = 1; off < 256; off <<= 1) {
        int add = (tid >= off) ? part[tid - off] : 0;
        __syncthreads();
        part[tid] += add;
        __syncthreads();
    }
    int run = part[tid] - s;
    if (t4 + 0 < NBUK) { lbase[t4 + 0] = run; run += l0; }
    if (t4 + 1 < NBUK) { lbase[t4 + 1] = run; run += l1; }
    if (t4 + 2 < NBUK) { lbase[t4 + 2] = run; run += l2; }
    if (t4 + 3 < NBUK) { lbase[t4 + 3] = run; run += l3; }
    // reserve global space per bucket
    for (int b = tid; b < NBUK; b += 256) {
        int h = hist[b];
        gbase[b] = h ? atomicAdd(&gcur[b], h) : 0;
    }
    __syncthreads();
    // scatter into LDS stage, grouped by bucket
    for (int k = tid; k < ecnt; k += 256) {
        int sN = ei[e0 + k];
        int d  = ei[N_EDGES + e0 + k];
        int b = d >> 7;
        int slot = lbase[b] + atomicAdd(&lcur[b], 1);
        stage[slot] = (uint32)sN | ((uint32)(d & 127) << 17);
        sbid[slot] = (unsigned short)b;
    }
    __syncthreads();
    // writeback: bucket-contiguous runs
    for (int k = tid; k < ecnt; k += 256) {
        int b = sbid[k];
        int r = gbase[b] + (k - lbase[b]);
        if (r < BCAP) pairs[(size_t)b * BCAP + r] = stage[k];
    }
}

// ---------------- dinv: per-bucket degree histogram ----------------
__global__ __launch_bounds__(256) void dinvk_kernel(const uint32* __restrict__ pairs,
                                                    const int* __restrict__ gcur,
                                                    float* __restrict__ dinv) {
    __shared__ int cnt[128];
    int b = blockIdx.x, tid = threadIdx.x;
    if (tid < 128) cnt[tid] = 0;
    __syncthreads();
    int n = gcur[b]; if (n > BCAP) n = BCAP;
    const uint32* pb = pairs + (size_t)b * BCAP;
    for (int k = tid; k < n; k += 256) atomicAdd(&cnt[pb[k] >> 17], 1);
    __syncthreads();
    int node = (b << 7) + tid;
    if (tid < 128 && node < N_NODES) dinv[node] = rsqrtf((float)(cnt[tid] + 1));
}

// ---------------- GEMM1: t1h[hf][node][32] = bf16(dinv[i]*(x@W1)) half-plane rows ----
__global__ __launch_bounds__(256) void gemm1_kernel(const float* __restrict__ x,
                                                    const float* __restrict__ W1,
                                                    const float* __restrict__ dinv,
                                                    unsigned short* __restrict__ t1h) {
    __shared__ float Ws[IN_F * HID_F];  // 32 KB
    int tid = threadIdx.x;
    for (int k = tid; k < IN_F * HID_F; k += 256) Ws[k] = W1[k];
    __syncthreads();
    int j = tid & 63;
    int nl = tid >> 6;
    int ibase = blockIdx.x * 16 + nl * 4;   // 6250*16 = 100000 exact
    const float4* r0 = (const float4*)(x + (size_t)(ibase + 0) * IN_F);
    const float4* r1 = (const float4*)(x + (size_t)(ibase + 1) * IN_F);
    const float4* r2 = (const float4*)(x + (size_t)(ibase + 2) * IN_F);
    const float4* r3 = (const float4*)(x + (size_t)(ibase + 3) * IN_F);
    float a0 = 0.f, a1 = 0.f, a2 = 0.f, a3 = 0.f;
#pragma unroll 4
    for (int k4 = 0; k4 < IN_F / 4; k4++) {
        float4 v0 = r0[k4], v1 = r1[k4], v2 = r2[k4], v3 = r3[k4];
        int k = k4 * 4;
        float w0 = Ws[(k + 0) * HID_F + j];
        float w1 = Ws[(k + 1) * HID_F + j];
        float w2 = Ws[(k + 2) * HID_F + j];
        float w3 = Ws[(k + 3) * HID_F + j];
        a0 += v0.x * w0 + v0.y * w1 + v0.z * w2 + v0.w * w3;
        a1 += v1.x * w0 + v1.y * w1 + v1.z * w2 + v1.w * w3;
        a2 += v2.x * w0 + v2.y * w1 + v2.z * w2 + v2.w * w3;
        a3 += v3.x * w0 + v3.y * w1 + v3.z * w2 + v3.w * w3;
    }
    // half-plane layout: addr = ((j>>5)*N + node)*32 + (j&31)
    size_t base = ((size_t)(j >> 5) * N_NODES + ibase) * 32 + (j & 31);
    t1h[base + 0 * 32] = f2bf(a0 * dinv[ibase + 0]);
    t1h[base + 1 * 32] = f2bf(a1 * dinv[ibase + 1]);
    t1h[base + 2 * 32] = f2bf(a2 * dinv[ibase + 2]);
    t1h[base + 3 * 32] = f2bf(a3 * dinv[ibase + 3]);
}

// ---------------- agg1: block = (bucket, feature-half); LDS fp32 atomic scatter ----
__global__ __launch_bounds__(256) void agg1_kernel(const unsigned short* __restrict__ t1h,
                                                   const uint32* __restrict__ pairs,
                                                   const int* __restrict__ gcur,
                                                   const float* __restrict__ dinv,
                                                   const float* __restrict__ b1,
                                                   float* __restrict__ h1) {
    __shared__ float acc[128 * 33];
    int b = blockIdx.x >> 1, hf = blockIdx.x & 1;
    int tid = threadIdx.x;
    for (int i = tid; i < 128 * 33; i += 256) acc[i] = 0.f;
    __syncthreads();
    int cnt = gcur[b]; if (cnt > BCAP) cnt = BCAP;
    const uint32* pb = pairs + (size_t)b * BCAP;
    const uint32* plane = (const uint32*)t1h + (size_t)hf * N_NODES * 16;
    int sl = tid >> 4;   // 0..15 edge slot
    int fu = tid & 15;   // uint within 64 B row
    int kb = 0;
    for (; kb + 32 <= cnt; kb += 32) {
        uint32 e0 = pb[kb + sl], e1 = pb[kb + 16 + sl];
        uint32 u0 = plane[(e0 & 0x1FFFF) * 16 + fu];
        uint32 u1 = plane[(e1 & 0x1FFFF) * 16 + fu];
        int a0 = (int)(e0 >> 17) * 33 + 2 * fu;
        int a1 = (int)(e1 >> 17) * 33 + 2 * fu;
        atomicAdd(&acc[a0], bflo(u0));
        atomicAdd(&acc[a0 + 1], bfhi(u0));
        atomicAdd(&acc[a1], bflo(u1));
        atomicAdd(&acc[a1 + 1], bfhi(u1));
    }
    if (kb + 16 <= cnt) {
        uint32 e0 = pb[kb + sl];
        uint32 u0 = plane[(e0 & 0x1FFFF) * 16 + fu];
        int a0 = (int)(e0 >> 17) * 33 + 2 * fu;
        atomicAdd(&acc[a0], bflo(u0));
        atomicAdd(&acc[a0 + 1], bfhi(u0));
        kb += 16;
    }
    if (kb + sl < cnt) {
        uint32 e0 = pb[kb + sl];
        uint32 u0 = plane[(e0 & 0x1FFFF) * 16 + fu];
        int a0 = (int)(e0 >> 17) * 33 + 2 * fu;
        atomicAdd(&acc[a0], bflo(u0));
        atomicAdd(&acc[a0 + 1], bfhi(u0));
    }
    __syncthreads();
    int node0 = b << 7;
    for (int idx = tid; idx < 128 * 32; idx += 256) {
        int nl = idx >> 5, f = idx & 31;
        int node = node0 + nl;
        if (node < N_NODES) {
            uint32 su = plane[node * 16 + (f >> 1)];
            float sv = (f & 1) ? bfhi(su) : bflo(su);
            float v = dinv[node] * (acc[nl * 33 + f] + sv) + b1[hf * 32 + f];
            h1[(size_t)node * HID_F + hf * 32 + f] = fmaxf(v, 0.f);
        }
    }
}

// ---------------- GEMM2: t2s = bf16(dinv[i]*(h1@W2)) row-major [N,32] ----------------
__global__ __launch_bounds__(256) void gemm2_kernel(const float* __restrict__ h1,
                                                    const float* __restrict__ W2,
                                                    const float* __restrict__ dinv,
                                                    unsigned short* __restrict__ t2s) {
    __shared__ float Ws[HID_F * Z_F];  // 8 KB
    int tid = threadIdx.x;
    for (int k = tid; k < HID_F * Z_F; k += 256) Ws[k] = W2[k];
    __syncthreads();
    int j = tid & 31;
    int nl = tid >> 5;
    int ibase = blockIdx.x * 32 + nl * 4;   // 3125*32 = 100000 exact
    const float4* r0 = (const float4*)(h1 + (size_t)(ibase + 0) * HID_F);
    const float4* r1 = (const float4*)(h1 + (size_t)(ibase + 1) * HID_F);
    const float4* r2 = (const float4*)(h1 + (size_t)(ibase + 2) * HID_F);
    const float4* r3 = (const float4*)(h1 + (size_t)(ibase + 3) * HID_F);
    float a0 = 0.f, a1 = 0.f, a2 = 0.f, a3 = 0.f;
#pragma unroll 4
    for (int k4 = 0; k4 < HID_F / 4; k4++) {
        float4 v0 = r0[k4], v1 = r1[k4], v2 = r2[k4], v3 = r3[k4];
        int k = k4 * 4;
        float w0 = Ws[(k + 0) * Z_F + j];
        float w1 = Ws[(k + 1) * Z_F + j];
        float w2 = Ws[(k + 2) * Z_F + j];
        float w3 = Ws[(k + 3) * Z_F + j];
        a0 += v0.x * w0 + v0.y * w1 + v0.z * w2 + v0.w * w3;
        a1 += v1.x * w0 + v1.y * w1 + v1.z * w2 + v1.w * w3;
        a2 += v2.x * w0 + v2.y * w1 + v2.z * w2 + v2.w * w3;
        a3 += v3.x * w0 + v3.y * w1 + v3.z * w2 + v3.w * w3;
    }
    t2s[(size_t)(ibase + 0) * Z_F + j] = f2bf(a0 * dinv[ibase + 0]);
    t2s[(size_t)(ibase + 1) * Z_F + j] = f2bf(a1 * dinv[ibase + 1]);
    t2s[(size_t)(ibase + 2) * Z_F + j] = f2bf(a2 * dinv[ibase + 2]);
    t2s[(size_t)(ibase + 3) * Z_F + j] = f2bf(a3 * dinv[ibase + 3]);
}

// ---------------- agg2: block = bucket; 32 feats in one pass ----------------
__global__ __launch_bounds__(256) void agg2_kernel(const unsigned short* __restrict__ t2s,
                                                   const uint32* __restrict__ pairs,
                                                   const int* __restrict__ gcur,
                                                   const float* __restrict__ dinv,
                                                   const float* __restrict__ b2,
                                                   float* __restrict__ h2) {
    __shared__ float acc[128 * 33];
    int b = blockIdx.x;
    int tid = threadIdx.x;
    for (int i = tid; i < 128 * 33; i += 256) acc[i] = 0.f;
    __syncthreads();
    int cnt = gcur[b]; if (cnt > BCAP) cnt = BCAP;
    const uint32* pb = pairs + (size_t)b * BCAP;
    const uint32* plane = (const uint32*)t2s;
    int sl = tid >> 4;
    int fu = tid & 15;
    int kb = 0;
    for (; kb + 32 <= cnt; kb += 32) {
        uint32 e0 = pb[kb + sl], e1 = pb[kb + 16 + sl];
        uint32 u0 = plane[(e0 & 0x1FFFF) * 16 + fu];
        uint32 u1 = plane[(e1 & 0x1FFFF) * 16 + fu];
        int a0 = (int)(e0 >> 17) * 33 + 2 * fu;
        int a1 = (int)(e1 >> 17) * 33 + 2 * fu;
        atomicAdd(&acc[a0], bflo(u0));
        atomicAdd(&acc[a0 + 1], bfhi(u0));
        atomicAdd(&acc[a1], bflo(u1));
        atomicAdd(&acc[a1 + 1], bfhi(u1));
    }
    if (kb + 16 <= cnt) {
        uint32 e0 = pb[kb + sl];
        uint32 u0 = plane[(e0 & 0x1FFFF) * 16 + fu];
        int a0 = (int)(e0 >> 17) * 33 + 2 * fu;
        atomicAdd(&acc[a0], bflo(u0));
        atomicAdd(&acc[a0 + 1], bfhi(u0));
        kb += 16;
    }
    if (kb + sl < cnt) {
        uint32 e0 = pb[kb + sl];
        uint32 u0 = plane[(e0 & 0x1FFFF) * 16 + fu];
        int a0 = (int)(e0 >> 17) * 33 + 2 * fu;
        atomicAdd(&acc[a0], bflo(u0));
        atomicAdd(&acc[a0 + 1], bfhi(u0));
    }
    __syncthreads();
    int node0 = b << 7;
    for (int idx = tid; idx < 128 * 32; idx += 256) {
        int nl = idx >> 5, f = idx & 31;
        int node = node0 + nl;
        if (node < N_NODES) {
            uint32 su = plane[node * 16 + (f >> 1)];
            float sv = (f & 1) ? bfhi(su) : bflo(su);
            float v = dinv[node] * (acc[nl * 33 + f] + sv) + b2[f];
            h2[(size_t)node * Z_F + f] = v;
        }
    }
}

// ---------------- heads: mu = h2@Wmu+bmu, lv = h2@Wlv+blv ----------------
__global__ __launch_bounds__(256) void heads_kernel(const float* __restrict__ h2,
                                                    const float* __restrict__ Wmu,
                                                    const float* __restrict__ bmu,
                                                    const float* __restrict__ Wlv,
                                                    const float* __restrict__ blv,
                                                    float* __restrict__ out) {
    __shared__ float Wm[Z_F * Z_F], Wl[Z_F * Z_F], bm[Z_F], bl[Z_F];
    int tid = threadIdx.x;
    for (int k = tid; k < Z_F * Z_F; k += 256) {
        Wm[k] = Wmu[k];
        Wl[k] = Wlv[k];
    }
    if (tid < Z_F) {
        bm[tid] = bmu[tid];
        bl[tid] = blv[tid];
    }
    __syncthreads();
    int j = tid & 31;
    int nl = tid >> 5;
    int i = blockIdx.x * 8 + nl;   // 12500*8 = 100000 exact
    const float* hr = h2 + (size_t)i * Z_F;
    float am = bm[j], al = bl[j];
#pragma unroll 8
    for (int k = 0; k < Z_F; k++) {
        float hv = hr[k];
        am += hv * Wm[k * Z_F + j];
        al += hv * Wl[k * Z_F + j];
    }
    out[(size_t)i * Z_F + j] = am;
    out[(size_t)N_NODES * Z_F + (size_t)i * Z_F + j] = al;
}

extern "C" void kernel_launch(void* const* d_in, const int* in_sizes, int n_in,
                              void* d_out, int out_size, void* d_ws, size_t ws_size,
                              hipStream_t stream) {
    const float* x   = (const float*)d_in[0];
    const int*   ei  = (const int*)d_in[1];
    const float* W1  = (const float*)d_in[2];
    const float* b1  = (const float*)d_in[3];
    const float* W2  = (const float*)d_in[4];
    const float* b2  = (const float*)d_in[5];
    const float* Wmu = (const float*)d_in[6];
    const float* bmu = (const float*)d_in[7];
    const float* Wlv = (const float*)d_in[8];
    const float* blv = (const float*)d_in[9];
    float* out = (float*)d_out;

    char* ws = (char*)d_ws;
    size_t off = 0;
    auto A = [&](size_t bytes) {
        size_t r = off;
        off += (bytes + 255) & ~(size_t)255;
        return r;
    };
    int*   gcur  = (int*)(ws + A((size_t)NBUK * 4));
    float* dinv  = (float*)(ws + A((size_t)N_NODES * 4));
    uint32* pairs = (uint32*)(ws + A((size_t)NBUK * BCAP * 4));                 // 9.6 MB (live thru agg2)
    unsigned short* t1h = (unsigned short*)(ws + A((size_t)N_NODES * HID_F * 2)); // 12.8 MB, dead after agg1
    float* h2 = (float*)t1h;                                                    // overlay: agg2 writes over dead t1h
    float* h1    = (float*)(ws + A((size_t)N_NODES * HID_F * 4));               // 25.6 MB
    unsigned short* t2s = (unsigned short*)(ws + A((size_t)N_NODES * Z_F * 2)); // 6.4 MB

    hipMemsetAsync(gcur, 0, (size_t)NBUK * 4, stream);

    phase1_kernel<<<P1_BLOCKS, 256, 0, stream>>>(ei, gcur, pairs);
    dinvk_kernel<<<NBUK, 256, 0, stream>>>(pairs, gcur, dinv);
    gemm1_kernel<<<N_NODES / 16, 256, 0, stream>>>(x, W1, dinv, t1h);
    agg1_kernel<<<NBUK * 2, 256, 0, stream>>>(t1h, pairs, gcur, dinv, b1, h1);
    gemm2_kernel<<<N_NODES / 32, 256, 0, stream>>>(h1, W2, dinv, t2s);
    agg2_kernel<<<NBUK, 256, 0, stream>>>(t2s, pairs, gcur, dinv, b2, h2);
    heads_kernel<<<N_NODES / 8, 256, 0, stream>>>(h2, Wmu, bmu, Wlv, blv, out);
}

// Round 5
// 395.566 us; speedup vs baseline: 3.1331x; 3.1331x over previous
//
#include <hip/hip_runtime.h>

#define N_NODES 100000
#define N_EDGES 1600000
#define IN_F   128
#define HID_F  64
#define Z_F    32
#define NBUK   782          // ceil(100000/128) buckets of 128 dst nodes
#define BCAP   3072         // bucket capacity (mean 2046, sigma ~45)
#define P1T    2048         // edges per phase1 block
#define P1_BLOCKS ((N_EDGES + P1T - 1) / P1T)   // 782

typedef unsigned int uint32;

__device__ __forceinline__ unsigned short f2bf(float f) {
    unsigned u = __float_as_uint(f);
    u = (u + 0x7FFF + ((u >> 16) & 1)) >> 16;   // RNE
    return (unsigned short)u;
}
__device__ __forceinline__ float bflo(uint32 u) { return __uint_as_float(u << 16); }
__device__ __forceinline__ float bfhi(uint32 u) { return __uint_as_float(u & 0xFFFF0000u); }

// ---------------- phase 1: bucket partition with LDS-staged chunked writeback ----
// pairs entry: src (17 bits) | local_dst (7 bits) << 17, grouped by bucket.
__global__ __launch_bounds__(256) void phase1_kernel(const int* __restrict__ ei,
                                                     int* __restrict__ gcur,
                                                     uint32* __restrict__ pairs) {
    __shared__ int hist[NBUK];
    __shared__ int lbase[NBUK];
    __shared__ int gbase[NBUK];
    __shared__ int lcur[NBUK];
    __shared__ uint32 stage[P1T];
    __shared__ unsigned short sbid[P1T];
    __shared__ int part[256];
    int tid = threadIdx.x;
    int e0 = blockIdx.x * P1T;
    int ecnt = N_EDGES - e0; if (ecnt > P1T) ecnt = P1T;
    for (int b = tid; b < NBUK; b += 256) { hist[b] = 0; lcur[b] = 0; }
    __syncthreads();
    for (int k = tid; k < ecnt; k += 256)
        atomicAdd(&hist[ei[N_EDGES + e0 + k] >> 7], 1);
    __syncthreads();
    int t4 = tid * 4;
    int l0 = 0, l1 = 0, l2 = 0, l3 = 0, s = 0;
    if (t4 + 0 < NBUK) { l0 = hist[t4 + 0]; s += l0; }
    if (t4 + 1 < NBUK) { l1 = hist[t4 + 1]; s += l1; }
    if (t4 + 2 < NBUK) { l2 = hist[t4 + 2]; s += l2; }
    if (t4 + 3 < NBUK) { l3 = hist[t4 + 3]; s += l3; }
    part[tid] = s;
    __syncthreads();
    for (int off = 1; off < 256; off <<= 1) {
        int add = (tid >= off) ? part[tid - off] : 0;
        __syncthreads();
        part[tid] += add;
        __syncthreads();
    }
    int run = part[tid] - s;
    if (t4 + 0 < NBUK) { lbase[t4 + 0] = run; run += l0; }
    if (t4 + 1 < NBUK) { lbase[t4 + 1] = run; run += l1; }
    if (t4 + 2 < NBUK) { lbase[t4 + 2] = run; run += l2; }
    if (t4 + 3 < NBUK) { lbase[t4 + 3] = run; run += l3; }
    for (int b = tid; b < NBUK; b += 256) {
        int h = hist[b];
        gbase[b] = h ? atomicAdd(&gcur[b], h) : 0;
    }
    __syncthreads();
    for (int k = tid; k < ecnt; k += 256) {
        int sN = ei[e0 + k];
        int d  = ei[N_EDGES + e0 + k];
        int b = d >> 7;
        int slot = lbase[b] + atomicAdd(&lcur[b], 1);
        stage[slot] = (uint32)sN | ((uint32)(d & 127) << 17);
        sbid[slot] = (unsigned short)b;
    }
    __syncthreads();
    for (int k = tid; k < ecnt; k += 256) {
        int b = sbid[k];
        int r = gbase[b] + (k - lbase[b]);
        if (r < BCAP) pairs[(size_t)b * BCAP + r] = stage[k];
    }
}

// ---------------- bucket scan ----------------
__global__ void bucketscan_kernel(const int* __restrict__ gcur,
                                  int* __restrict__ bucketBase,
                                  int* __restrict__ rowptr) {
    __shared__ int s[1024];
    int t = threadIdx.x;
    int v = (t < NBUK) ? gcur[t] : 0;
    s[t] = v;
    __syncthreads();
    for (int off = 1; off < 1024; off <<= 1) {
        int add = (t >= off) ? s[t - off] : 0;
        __syncthreads();
        s[t] += add;
        __syncthreads();
    }
    if (t < NBUK) bucketBase[t] = s[t] - v;
    if (t == 0) rowptr[N_NODES] = N_EDGES;
}

// ---------------- phase 2: per-bucket CSR build (coalesced writes, LDS scatter) ----
__global__ __launch_bounds__(256) void phase2_kernel(const uint32* __restrict__ pairs,
                                                     const int* __restrict__ gcur,
                                                     const int* __restrict__ bucketBase,
                                                     int* __restrict__ rowptr,
                                                     float* __restrict__ dinv,
                                                     int* __restrict__ col) {
    __shared__ int lhist[128];
    __shared__ int lscan[128];
    __shared__ int lcur[128];
    __shared__ int stage[BCAP];
    int b = blockIdx.x;
    int tid = threadIdx.x;
    int cnt_b = gcur[b];
    if (cnt_b > BCAP) cnt_b = BCAP;
    int gbase = bucketBase[b];
    int node0 = b << 7;
    int nb = N_NODES - node0;
    if (nb > 128) nb = 128;
    if (tid < 128) { lhist[tid] = 0; lcur[tid] = 0; }
    __syncthreads();
    const uint32* pb = pairs + (size_t)b * BCAP;
    for (int k = tid; k < cnt_b; k += 256) atomicAdd(&lhist[pb[k] >> 17], 1);
    __syncthreads();
    int v = (tid < 128) ? lhist[tid] : 0;
    if (tid < 128) lscan[tid] = v;
    __syncthreads();
    for (int off = 1; off < 128; off <<= 1) {
        int add = (tid < 128 && tid >= off) ? lscan[tid - off] : 0;
        __syncthreads();
        if (tid < 128) lscan[tid] += add;
        __syncthreads();
    }
    if (tid < 128) lscan[tid] -= v;  // exclusive
    __syncthreads();
    if (tid < nb) {
        rowptr[node0 + tid] = gbase + lscan[tid];
        dinv[node0 + tid] = rsqrtf((float)(lhist[tid] + 1));
    }
    for (int k = tid; k < cnt_b; k += 256) {
        uint32 u = pb[k];
        int ld = u >> 17;
        int r = atomicAdd(&lcur[ld], 1);
        stage[lscan[ld] + r] = (int)(u & 0x1FFFF);
    }
    __syncthreads();
    for (int k = tid; k < cnt_b; k += 256) col[gbase + k] = stage[k];
}

// ---------------- GEMM1: t1 = bf16(dinv[i] * (x@W1)) row-major [N,64] ----------------
__global__ __launch_bounds__(256) void gemm1_kernel(const float* __restrict__ x,
                                                    const float* __restrict__ W1,
                                                    const float* __restrict__ dinv,
                                                    unsigned short* __restrict__ t1) {
    __shared__ float Ws[IN_F * HID_F];  // 32 KB
    int tid = threadIdx.x;
    for (int k = tid; k < IN_F * HID_F; k += 256) Ws[k] = W1[k];
    __syncthreads();
    int j = tid & 63;
    int nl = tid >> 6;
    int ibase = blockIdx.x * 16 + nl * 4;   // 6250*16 = 100000 exact
    const float4* r0 = (const float4*)(x + (size_t)(ibase + 0) * IN_F);
    const float4* r1 = (const float4*)(x + (size_t)(ibase + 1) * IN_F);
    const float4* r2 = (const float4*)(x + (size_t)(ibase + 2) * IN_F);
    const float4* r3 = (const float4*)(x + (size_t)(ibase + 3) * IN_F);
    float a0 = 0.f, a1 = 0.f, a2 = 0.f, a3 = 0.f;
#pragma unroll 4
    for (int k4 = 0; k4 < IN_F / 4; k4++) {
        float4 v0 = r0[k4], v1 = r1[k4], v2 = r2[k4], v3 = r3[k4];
        int k = k4 * 4;
        float w0 = Ws[(k + 0) * HID_F + j];
        float w1 = Ws[(k + 1) * HID_F + j];
        float w2 = Ws[(k + 2) * HID_F + j];
        float w3 = Ws[(k + 3) * HID_F + j];
        a0 += v0.x * w0 + v0.y * w1 + v0.z * w2 + v0.w * w3;
        a1 += v1.x * w0 + v1.y * w1 + v1.z * w2 + v1.w * w3;
        a2 += v2.x * w0 + v2.y * w1 + v2.z * w2 + v2.w * w3;
        a3 += v3.x * w0 + v3.y * w1 + v3.z * w2 + v3.w * w3;
    }
    t1[(size_t)(ibase + 0) * HID_F + j] = f2bf(a0 * dinv[ibase + 0]);
    t1[(size_t)(ibase + 1) * HID_F + j] = f2bf(a1 * dinv[ibase + 1]);
    t1[(size_t)(ibase + 2) * HID_F + j] = f2bf(a2 * dinv[ibase + 2]);
    t1[(size_t)(ibase + 3) * HID_F + j] = f2bf(a3 * dinv[ibase + 3]);
}

// ---------------- agg1: single pass, 128B rows, 4 edges/inst, unroll 4 ----------------
// wave = node; slot = lane>>4 (4 edge slots); fu = lane&15 (uint2 -> feats 4fu..4fu+3)
__global__ __launch_bounds__(256) void agg1_kernel(const unsigned short* __restrict__ t1,
                                                   const int* __restrict__ rowptr,
                                                   const int* __restrict__ col,
                                                   const float* __restrict__ dinv,
                                                   const float* __restrict__ b1,
                                                   float* __restrict__ h1) {
    int lane = threadIdx.x & 63;
    int slot = lane >> 4;
    int fu = lane & 15;
    int i = blockIdx.x * 4 + (threadIdx.x >> 6);
    int s = rowptr[i], e = rowptr[i + 1];
    const uint2* t1v = (const uint2*)t1;   // row stride 16 uint2
    float a0 = 0.f, a1 = 0.f, a2 = 0.f, a3 = 0.f;
    int p = s + slot;
    for (; p + 12 < e; p += 16) {
        int c0 = col[p], c1 = col[p + 4], c2 = col[p + 8], c3 = col[p + 12];
        uint2 u0 = t1v[(size_t)c0 * 16 + fu];
        uint2 u1 = t1v[(size_t)c1 * 16 + fu];
        uint2 u2 = t1v[(size_t)c2 * 16 + fu];
        uint2 u3 = t1v[(size_t)c3 * 16 + fu];
        a0 += bflo(u0.x) + bflo(u1.x) + bflo(u2.x) + bflo(u3.x);
        a1 += bfhi(u0.x) + bfhi(u1.x) + bfhi(u2.x) + bfhi(u3.x);
        a2 += bflo(u0.y) + bflo(u1.y) + bflo(u2.y) + bflo(u3.y);
        a3 += bfhi(u0.y) + bfhi(u1.y) + bfhi(u2.y) + bfhi(u3.y);
    }
    for (; p < e; p += 4) {
        uint2 u = t1v[(size_t)col[p] * 16 + fu];
        a0 += bflo(u.x); a1 += bfhi(u.x);
        a2 += bflo(u.y); a3 += bfhi(u.y);
    }
    a0 += __shfl_xor(a0, 16, 64); a1 += __shfl_xor(a1, 16, 64);
    a2 += __shfl_xor(a2, 16, 64); a3 += __shfl_xor(a3, 16, 64);
    a0 += __shfl_xor(a0, 32, 64); a1 += __shfl_xor(a1, 32, 64);
    a2 += __shfl_xor(a2, 32, 64); a3 += __shfl_xor(a3, 32, 64);
    if (slot == 0) {
        uint2 us = t1v[(size_t)i * 16 + fu];   // self (already dinv[i]-scaled)
        float di = dinv[i];
        float4 bb = ((const float4*)b1)[fu];
        float4 o;
        o.x = fmaxf(di * (a0 + bflo(us.x)) + bb.x, 0.f);
        o.y = fmaxf(di * (a1 + bfhi(us.x)) + bb.y, 0.f);
        o.z = fmaxf(di * (a2 + bflo(us.y)) + bb.z, 0.f);
        o.w = fmaxf(di * (a3 + bfhi(us.y)) + bb.w, 0.f);
        ((float4*)(h1 + (size_t)i * HID_F))[fu] = o;
    }
}

// ---------------- GEMM2: t2 = bf16(dinv[i]*(h1@W2)) row-major [N,32] ----------------
__global__ __launch_bounds__(256) void gemm2_kernel(const float* __restrict__ h1,
                                                    const float* __restrict__ W2,
                                                    const float* __restrict__ dinv,
                                                    unsigned short* __restrict__ t2s) {
    __shared__ float Ws[HID_F * Z_F];  // 8 KB
    int tid = threadIdx.x;
    for (int k = tid; k < HID_F * Z_F; k += 256) Ws[k] = W2[k];
    __syncthreads();
    int j = tid & 31;
    int nl = tid >> 5;
    int ibase = blockIdx.x * 32 + nl * 4;   // 3125*32 = 100000 exact
    const float4* r0 = (const float4*)(h1 + (size_t)(ibase + 0) * HID_F);
    const float4* r1 = (const float4*)(h1 + (size_t)(ibase + 1) * HID_F);
    const float4* r2 = (const float4*)(h1 + (size_t)(ibase + 2) * HID_F);
    const float4* r3 = (const float4*)(h1 + (size_t)(ibase + 3) * HID_F);
    float a0 = 0.f, a1 = 0.f, a2 = 0.f, a3 = 0.f;
#pragma unroll 4
    for (int k4 = 0; k4 < HID_F / 4; k4++) {
        float4 v0 = r0[k4], v1 = r1[k4], v2 = r2[k4], v3 = r3[k4];
        int k = k4 * 4;
        float w0 = Ws[(k + 0) * Z_F + j];
        float w1 = Ws[(k + 1) * Z_F + j];
        float w2 = Ws[(k + 2) * Z_F + j];
        float w3 = Ws[(k + 3) * Z_F + j];
        a0 += v0.x * w0 + v0.y * w1 + v0.z * w2 + v0.w * w3;
        a1 += v1.x * w0 + v1.y * w1 + v1.z * w2 + v1.w * w3;
        a2 += v2.x * w0 + v2.y * w1 + v2.z * w2 + v2.w * w3;
        a3 += v3.x * w0 + v3.y * w1 + v3.z * w2 + v3.w * w3;
    }
    t2s[(size_t)(ibase + 0) * Z_F + j] = f2bf(a0 * dinv[ibase + 0]);
    t2s[(size_t)(ibase + 1) * Z_F + j] = f2bf(a1 * dinv[ibase + 1]);
    t2s[(size_t)(ibase + 2) * Z_F + j] = f2bf(a2 * dinv[ibase + 2]);
    t2s[(size_t)(ibase + 3) * Z_F + j] = f2bf(a3 * dinv[ibase + 3]);
}

// ---------------- agg2: single pass, 64B rows, 8 edges/inst, unroll 2 ----------------
// slot = lane>>3 (8 slots); fu = lane&7 (uint2 -> feats 4fu..4fu+3)
__global__ __launch_bounds__(256) void agg2_kernel(const unsigned short* __restrict__ t2s,
                                                   const int* __restrict__ rowptr,
                                                   const int* __restrict__ col,
                                                   const float* __restrict__ dinv,
                                                   const float* __restrict__ b2,
                                                   float* __restrict__ h2) {
    int lane = threadIdx.x & 63;
    int slot = lane >> 3;
    int fu = lane & 7;
    int i = blockIdx.x * 4 + (threadIdx.x >> 6);
    int s = rowptr[i], e = rowptr[i + 1];
    const uint2* t2v = (const uint2*)t2s;   // row stride 8 uint2
    float a0 = 0.f, a1 = 0.f, a2 = 0.f, a3 = 0.f;
    int p = s + slot;
    for (; p + 8 < e; p += 16) {
        int c0 = col[p], c1 = col[p + 8];
        uint2 u0 = t2v[(size_t)c0 * 8 + fu];
        uint2 u1 = t2v[(size_t)c1 * 8 + fu];
        a0 += bflo(u0.x) + bflo(u1.x);
        a1 += bfhi(u0.x) + bfhi(u1.x);
        a2 += bflo(u0.y) + bflo(u1.y);
        a3 += bfhi(u0.y) + bfhi(u1.y);
    }
    for (; p < e; p += 8) {
        uint2 u = t2v[(size_t)col[p] * 8 + fu];
        a0 += bflo(u.x); a1 += bfhi(u.x);
        a2 += bflo(u.y); a3 += bfhi(u.y);
    }
    a0 += __shfl_xor(a0, 8, 64);  a1 += __shfl_xor(a1, 8, 64);
    a2 += __shfl_xor(a2, 8, 64);  a3 += __shfl_xor(a3, 8, 64);
    a0 += __shfl_xor(a0, 16, 64); a1 += __shfl_xor(a1, 16, 64);
    a2 += __shfl_xor(a2, 16, 64); a3 += __shfl_xor(a3, 16, 64);
    a0 += __shfl_xor(a0, 32, 64); a1 += __shfl_xor(a1, 32, 64);
    a2 += __shfl_xor(a2, 32, 64); a3 += __shfl_xor(a3, 32, 64);
    if (slot == 0) {
        uint2 us = t2v[(size_t)i * 8 + fu];
        float di = dinv[i];
        float4 bb = ((const float4*)b2)[fu];
        float4 o;
        o.x = di * (a0 + bflo(us.x)) + bb.x;
        o.y = di * (a1 + bfhi(us.x)) + bb.y;
        o.z = di * (a2 + bflo(us.y)) + bb.z;
        o.w = di * (a3 + bfhi(us.y)) + bb.w;
        ((float4*)(h2 + (size_t)i * Z_F))[fu] = o;
    }
}

// ---------------- heads: mu = h2@Wmu+bmu, lv = h2@Wlv+blv ----------------
__global__ __launch_bounds__(256) void heads_kernel(const float* __restrict__ h2,
                                                    const float* __restrict__ Wmu,
                                                    const float* __restrict__ bmu,
                                                    const float* __restrict__ Wlv,
                                                    const float* __restrict__ blv,
                                                    float* __restrict__ out) {
    __shared__ float Wm[Z_F * Z_F], Wl[Z_F * Z_F], bm[Z_F], bl[Z_F];
    int tid = threadIdx.x;
    for (int k = tid; k < Z_F * Z_F; k += 256) {
        Wm[k] = Wmu[k];
        Wl[k] = Wlv[k];
    }
    if (tid < Z_F) {
        bm[tid] = bmu[tid];
        bl[tid] = blv[tid];
    }
    __syncthreads();
    int j = tid & 31;
    int nl = tid >> 5;
    int i = blockIdx.x * 8 + nl;   // 12500*8 = 100000 exact
    const float* hr = h2 + (size_t)i * Z_F;
    float am = bm[j], al = bl[j];
#pragma unroll 8
    for (int k = 0; k < Z_F; k++) {
        float hv = hr[k];
        am += hv * Wm[k * Z_F + j];
        al += hv * Wl[k * Z_F + j];
    }
    out[(size_t)i * Z_F + j] = am;
    out[(size_t)N_NODES * Z_F + (size_t)i * Z_F + j] = al;
}

extern "C" void kernel_launch(void* const* d_in, const int* in_sizes, int n_in,
                              void* d_out, int out_size, void* d_ws, size_t ws_size,
                              hipStream_t stream) {
    const float* x   = (const float*)d_in[0];
    const int*   ei  = (const int*)d_in[1];
    const float* W1  = (const float*)d_in[2];
    const float* b1  = (const float*)d_in[3];
    const float* W2  = (const float*)d_in[4];
    const float* b2  = (const float*)d_in[5];
    const float* Wmu = (const float*)d_in[6];
    const float* bmu = (const float*)d_in[7];
    const float* Wlv = (const float*)d_in[8];
    const float* blv = (const float*)d_in[9];
    float* out = (float*)d_out;

    char* ws = (char*)d_ws;
    size_t off = 0;
    auto A = [&](size_t bytes) {
        size_t r = off;
        off += (bytes + 255) & ~(size_t)255;
        return r;
    };
    int*   gcur       = (int*)(ws + A((size_t)NBUK * 4));
    int*   bucketBase = (int*)(ws + A((size_t)NBUK * 4));
    int*   rowptr     = (int*)(ws + A((size_t)(N_NODES + 1) * 4));
    float* dinv       = (float*)(ws + A((size_t)N_NODES * 4));
    int*   col        = (int*)(ws + A((size_t)N_EDGES * 4));                    // 6.4 MB
    char*  reg1 = ws + A((size_t)NBUK * BCAP * 4);                              // 9.6 MB: pairs -> t2s
    uint32* pairs = (uint32*)reg1;           // dead after phase2
    unsigned short* t2s = (unsigned short*)reg1;  // 6.4 MB, written by gemm2
    char*  reg2 = ws + A((size_t)N_NODES * HID_F * 2);                          // 12.8 MB: t1 -> h2
    unsigned short* t1 = (unsigned short*)reg2;   // dead after agg1
    float* h2 = (float*)reg2;                // written by agg2
    float* h1 = (float*)(ws + A((size_t)N_NODES * HID_F * 4));                  // 25.6 MB

    hipMemsetAsync(gcur, 0, (size_t)NBUK * 4, stream);

    phase1_kernel<<<P1_BLOCKS, 256, 0, stream>>>(ei, gcur, pairs);
    bucketscan_kernel<<<1, 1024, 0, stream>>>(gcur, bucketBase, rowptr);
    phase2_kernel<<<NBUK, 256, 0, stream>>>(pairs, gcur, bucketBase, rowptr, dinv, col);

    gemm1_kernel<<<N_NODES / 16, 256, 0, stream>>>(x, W1, dinv, t1);
    agg1_kernel<<<N_NODES / 4, 256, 0, stream>>>(t1, rowptr, col, dinv, b1, h1);
    gemm2_kernel<<<N_NODES / 32, 256, 0, stream>>>(h1, W2, dinv, t2s);
    agg2_kernel<<<N_NODES / 4, 256, 0, stream>>>(t2s, rowptr, col, dinv, b2, h2);
    heads_kernel<<<N_NODES / 8, 256, 0, stream>>>(h2, Wmu, bmu, Wlv, blv, out);
}

// Round 6
// 327.952 us; speedup vs baseline: 3.7790x; 1.2062x over previous
//
#include <hip/hip_runtime.h>

#define N_NODES 100000
#define N_EDGES 1600000
#define IN_F   128
#define HID_F  64
#define Z_F    32
#define NBUK   782          // ceil(100000/128) buckets of 128 dst nodes
#define BCAP   3072         // bucket capacity (mean 2046, sigma ~45)
#define P1T    2048         // edges per phase1 block
#define P1_BLOCKS ((N_EDGES + P1T - 1) / P1T)   // 782

typedef unsigned int uint32;
typedef __attribute__((ext_vector_type(8))) short bf16x8;
typedef __attribute__((ext_vector_type(4))) float f32x4;

__device__ __forceinline__ unsigned short f2bf(float f) {
    unsigned u = __float_as_uint(f);
    u = (u + 0x7FFF + ((u >> 16) & 1)) >> 16;   // RNE
    return (unsigned short)u;
}
__device__ __forceinline__ float bflo(uint32 u) { return __uint_as_float(u << 16); }
__device__ __forceinline__ float bfhi(uint32 u) { return __uint_as_float(u & 0xFFFF0000u); }

// ---------------- phase 1: bucket partition with LDS-staged chunked writeback ----
__global__ __launch_bounds__(256) void phase1_kernel(const int* __restrict__ ei,
                                                     int* __restrict__ gcur,
                                                     uint32* __restrict__ pairs) {
    __shared__ int hist[NBUK];
    __shared__ int lbase[NBUK];
    __shared__ int gbase[NBUK];
    __shared__ int lcur[NBUK];
    __shared__ uint32 stage[P1T];
    __shared__ unsigned short sbid[P1T];
    __shared__ int part[256];
    int tid = threadIdx.x;
    int e0 = blockIdx.x * P1T;
    int ecnt = N_EDGES - e0; if (ecnt > P1T) ecnt = P1T;
    for (int b = tid; b < NBUK; b += 256) { hist[b] = 0; lcur[b] = 0; }
    __syncthreads();
    for (int k = tid; k < ecnt; k += 256)
        atomicAdd(&hist[ei[N_EDGES + e0 + k] >> 7], 1);
    __syncthreads();
    int t4 = tid * 4;
    int l0 = 0, l1 = 0, l2 = 0, l3 = 0, s = 0;
    if (t4 + 0 < NBUK) { l0 = hist[t4 + 0]; s += l0; }
    if (t4 + 1 < NBUK) { l1 = hist[t4 + 1]; s += l1; }
    if (t4 + 2 < NBUK) { l2 = hist[t4 + 2]; s += l2; }
    if (t4 + 3 < NBUK) { l3 = hist[t4 + 3]; s += l3; }
    part[tid] = s;
    __syncthreads();
    for (int off = 1; off < 256; off <<= 1) {
        int add = (tid >= off) ? part[tid - off] : 0;
        __syncthreads();
        part[tid] += add;
        __syncthreads();
    }
    int run = part[tid] - s;
    if (t4 + 0 < NBUK) { lbase[t4 + 0] = run; run += l0; }
    if (t4 + 1 < NBUK) { lbase[t4 + 1] = run; run += l1; }
    if (t4 + 2 < NBUK) { lbase[t4 + 2] = run; run += l2; }
    if (t4 + 3 < NBUK) { lbase[t4 + 3] = run; run += l3; }
    for (int b = tid; b < NBUK; b += 256) {
        int h = hist[b];
        gbase[b] = h ? atomicAdd(&gcur[b], h) : 0;
    }
    __syncthreads();
    for (int k = tid; k < ecnt; k += 256) {
        int sN = ei[e0 + k];
        int d  = ei[N_EDGES + e0 + k];
        int b = d >> 7;
        int slot = lbase[b] + atomicAdd(&lcur[b], 1);
        stage[slot] = (uint32)sN | ((uint32)(d & 127) << 17);
        sbid[slot] = (unsigned short)b;
    }
    __syncthreads();
    for (int k = tid; k < ecnt; k += 256) {
        int b = sbid[k];
        int r = gbase[b] + (k - lbase[b]);
        if (r < BCAP) pairs[(size_t)b * BCAP + r] = stage[k];
    }
}

// ---------------- bucket scan ----------------
__global__ void bucketscan_kernel(const int* __restrict__ gcur,
                                  int* __restrict__ bucketBase,
                                  int* __restrict__ rowptr) {
    __shared__ int s[1024];
    int t = threadIdx.x;
    int v = (t < NBUK) ? gcur[t] : 0;
    s[t] = v;
    __syncthreads();
    for (int off = 1; off < 1024; off <<= 1) {
        int add = (t >= off) ? s[t - off] : 0;
        __syncthreads();
        s[t] += add;
        __syncthreads();
    }
    if (t < NBUK) bucketBase[t] = s[t] - v;
    if (t == 0) rowptr[N_NODES] = N_EDGES;
}

// ---------------- phase 2: per-bucket CSR build (coalesced writes, LDS scatter) ----
__global__ __launch_bounds__(256) void phase2_kernel(const uint32* __restrict__ pairs,
                                                     const int* __restrict__ gcur,
                                                     const int* __restrict__ bucketBase,
                                                     int* __restrict__ rowptr,
                                                     float* __restrict__ dinv,
                                                     int* __restrict__ col) {
    __shared__ int lhist[128];
    __shared__ int lscan[128];
    __shared__ int lcur[128];
    __shared__ int stage[BCAP];
    int b = blockIdx.x;
    int tid = threadIdx.x;
    int cnt_b = gcur[b];
    if (cnt_b > BCAP) cnt_b = BCAP;
    int gbase = bucketBase[b];
    int node0 = b << 7;
    int nb = N_NODES - node0;
    if (nb > 128) nb = 128;
    if (tid < 128) { lhist[tid] = 0; lcur[tid] = 0; }
    __syncthreads();
    const uint32* pb = pairs + (size_t)b * BCAP;
    for (int k = tid; k < cnt_b; k += 256) atomicAdd(&lhist[pb[k] >> 17], 1);
    __syncthreads();
    int v = (tid < 128) ? lhist[tid] : 0;
    if (tid < 128) lscan[tid] = v;
    __syncthreads();
    for (int off = 1; off < 128; off <<= 1) {
        int add = (tid < 128 && tid >= off) ? lscan[tid - off] : 0;
        __syncthreads();
        if (tid < 128) lscan[tid] += add;
        __syncthreads();
    }
    if (tid < 128) lscan[tid] -= v;  // exclusive
    __syncthreads();
    if (tid < nb) {
        rowptr[node0 + tid] = gbase + lscan[tid];
        dinv[node0 + tid] = rsqrtf((float)(lhist[tid] + 1));
    }
    for (int k = tid; k < cnt_b; k += 256) {
        uint32 u = pb[k];
        int ld = u >> 17;
        int r = atomicAdd(&lcur[ld], 1);
        stage[lscan[ld] + r] = (int)(u & 0x1FFFF);
    }
    __syncthreads();
    for (int k = tid; k < cnt_b; k += 256) col[gbase + k] = stage[k];
}

// ---------------- GEMM1 (MFMA): t1 = bf16(dinv[i] * (x@W1)) row-major [N,64] --------
// Block = 64 nodes. A = x-tile bf16 in LDS, B = W1^T bf16 in LDS. 16x16x32 MFMA.
// Layouts (verified m89/m91): A[m=lane&15][k=quad*8+j], B[n=lane&15][k=quad*8+j],
// D: col=lane&15, row=quad*4+reg.
#define G1_STRIDE 136   // 128 + 8 pad (shorts); 272 B row, 16B-aligned, 2-way bank tier
#define G1_CSTR   72    // C staging stride (shorts); 144 B row

__global__ __launch_bounds__(256) void gemm1_kernel(const float* __restrict__ x,
                                                    const float* __restrict__ W1,
                                                    const float* __restrict__ dinv,
                                                    unsigned short* __restrict__ t1) {
    __shared__ unsigned short Xs[64 * G1_STRIDE];
    __shared__ unsigned short Wt[64 * G1_STRIDE];
    __shared__ float dv[64];
    int tid = threadIdx.x;
    int node0 = blockIdx.x * 64;
    // stage W1^T: Wt[n][k] = W1[k*64+n], coalesced fp32 reads
#pragma unroll
    for (int it = 0; it < 32; it++) {
        int idx = it * 256 + tid;            // 8192 = 128*64
        int k = idx >> 6, n = idx & 63;
        Wt[n * G1_STRIDE + k] = f2bf(W1[idx]);
    }
    // stage x rows node0..node0+63, coalesced fp32 reads
#pragma unroll
    for (int it = 0; it < 32; it++) {
        int idx = it * 256 + tid;            // 8192 = 64*128
        int r = idx >> 7, k = idx & 127;
        int node = node0 + r;
        float v = (node < N_NODES) ? x[(size_t)node * IN_F + k] : 0.f;
        Xs[r * G1_STRIDE + k] = f2bf(v);
    }
    if (tid < 64) {
        int node = node0 + tid;
        dv[tid] = (node < N_NODES) ? dinv[node] : 0.f;
    }
    __syncthreads();
    int w = tid >> 6;
    int lane = tid & 63;
    int m = lane & 15;
    int quad = lane >> 4;
    f32x4 acc0 = {0.f, 0.f, 0.f, 0.f};
    f32x4 acc1 = acc0, acc2 = acc0, acc3 = acc0;
#pragma unroll
    for (int ks = 0; ks < 4; ks++) {
        int kb = ks * 32 + quad * 8;
        bf16x8 a  = *(const bf16x8*)&Xs[(w * 16 + m) * G1_STRIDE + kb];
        bf16x8 b0 = *(const bf16x8*)&Wt[(0 * 16 + m) * G1_STRIDE + kb];
        bf16x8 b1 = *(const bf16x8*)&Wt[(1 * 16 + m) * G1_STRIDE + kb];
        bf16x8 b2 = *(const bf16x8*)&Wt[(2 * 16 + m) * G1_STRIDE + kb];
        bf16x8 b3 = *(const bf16x8*)&Wt[(3 * 16 + m) * G1_STRIDE + kb];
        acc0 = __builtin_amdgcn_mfma_f32_16x16x32_bf16(a, b0, acc0, 0, 0, 0);
        acc1 = __builtin_amdgcn_mfma_f32_16x16x32_bf16(a, b1, acc1, 0, 0, 0);
        acc2 = __builtin_amdgcn_mfma_f32_16x16x32_bf16(a, b2, acc2, 0, 0, 0);
        acc3 = __builtin_amdgcn_mfma_f32_16x16x32_bf16(a, b3, acc3, 0, 0, 0);
    }
    __syncthreads();   // Xs dead -> reuse as C staging
    unsigned short* Cs = Xs;
    int rbase = w * 16 + quad * 4;
#pragma unroll
    for (int reg = 0; reg < 4; reg++) {
        int row = rbase + reg;
        float d = dv[row];
        Cs[row * G1_CSTR +  0 + m] = f2bf(acc0[reg] * d);
        Cs[row * G1_CSTR + 16 + m] = f2bf(acc1[reg] * d);
        Cs[row * G1_CSTR + 32 + m] = f2bf(acc2[reg] * d);
        Cs[row * G1_CSTR + 48 + m] = f2bf(acc3[reg] * d);
    }
    __syncthreads();
    // coalesced writeback: 64 rows x 64 shorts in 8B chunks
#pragma unroll
    for (int it = 0; it < 4; it++) {
        int idx = it * 256 + tid;            // 1024 chunks
        int row = idx >> 4, c = idx & 15;
        int node = node0 + row;
        if (node < N_NODES) {
            uint2 vv = *(const uint2*)&Cs[row * G1_CSTR + c * 4];
            *(uint2*)&t1[(size_t)node * HID_F + c * 4] = vv;
        }
    }
}

// ---------------- agg1: single pass, 128B rows, 4 edges/inst, unroll 4 ----------------
__global__ __launch_bounds__(256) void agg1_kernel(const unsigned short* __restrict__ t1,
                                                   const int* __restrict__ rowptr,
                                                   const int* __restrict__ col,
                                                   const float* __restrict__ dinv,
                                                   const float* __restrict__ b1,
                                                   float* __restrict__ h1) {
    int lane = threadIdx.x & 63;
    int slot = lane >> 4;
    int fu = lane & 15;
    int i = blockIdx.x * 4 + (threadIdx.x >> 6);
    int s = rowptr[i], e = rowptr[i + 1];
    const uint2* t1v = (const uint2*)t1;   // row stride 16 uint2
    float a0 = 0.f, a1 = 0.f, a2 = 0.f, a3 = 0.f;
    int p = s + slot;
    for (; p + 12 < e; p += 16) {
        int c0 = col[p], c1 = col[p + 4], c2 = col[p + 8], c3 = col[p + 12];
        uint2 u0 = t1v[(size_t)c0 * 16 + fu];
        uint2 u1 = t1v[(size_t)c1 * 16 + fu];
        uint2 u2 = t1v[(size_t)c2 * 16 + fu];
        uint2 u3 = t1v[(size_t)c3 * 16 + fu];
        a0 += bflo(u0.x) + bflo(u1.x) + bflo(u2.x) + bflo(u3.x);
        a1 += bfhi(u0.x) + bfhi(u1.x) + bfhi(u2.x) + bfhi(u3.x);
        a2 += bflo(u0.y) + bflo(u1.y) + bflo(u2.y) + bflo(u3.y);
        a3 += bfhi(u0.y) + bfhi(u1.y) + bfhi(u2.y) + bfhi(u3.y);
    }
    for (; p < e; p += 4) {
        uint2 u = t1v[(size_t)col[p] * 16 + fu];
        a0 += bflo(u.x); a1 += bfhi(u.x);
        a2 += bflo(u.y); a3 += bfhi(u.y);
    }
    a0 += __shfl_xor(a0, 16, 64); a1 += __shfl_xor(a1, 16, 64);
    a2 += __shfl_xor(a2, 16, 64); a3 += __shfl_xor(a3, 16, 64);
    a0 += __shfl_xor(a0, 32, 64); a1 += __shfl_xor(a1, 32, 64);
    a2 += __shfl_xor(a2, 32, 64); a3 += __shfl_xor(a3, 32, 64);
    if (slot == 0) {
        uint2 us = t1v[(size_t)i * 16 + fu];   // self (already dinv[i]-scaled)
        float di = dinv[i];
        float4 bb = ((const float4*)b1)[fu];
        float4 o;
        o.x = fmaxf(di * (a0 + bflo(us.x)) + bb.x, 0.f);
        o.y = fmaxf(di * (a1 + bfhi(us.x)) + bb.y, 0.f);
        o.z = fmaxf(di * (a2 + bflo(us.y)) + bb.z, 0.f);
        o.w = fmaxf(di * (a3 + bfhi(us.y)) + bb.w, 0.f);
        ((float4*)(h1 + (size_t)i * HID_F))[fu] = o;
    }
}

// ---------------- GEMM2: t2 = bf16(dinv[i]*(h1@W2)) row-major [N,32] ----------------
__global__ __launch_bounds__(256) void gemm2_kernel(const float* __restrict__ h1,
                                                    const float* __restrict__ W2,
                                                    const float* __restrict__ dinv,
                                                    unsigned short* __restrict__ t2s) {
    __shared__ float Ws[HID_F * Z_F];  // 8 KB
    int tid = threadIdx.x;
    for (int k = tid; k < HID_F * Z_F; k += 256) Ws[k] = W2[k];
    __syncthreads();
    int j = tid & 31;
    int nl = tid >> 5;
    int ibase = blockIdx.x * 32 + nl * 4;   // 3125*32 = 100000 exact
    const float4* r0 = (const float4*)(h1 + (size_t)(ibase + 0) * HID_F);
    const float4* r1 = (const float4*)(h1 + (size_t)(ibase + 1) * HID_F);
    const float4* r2 = (const float4*)(h1 + (size_t)(ibase + 2) * HID_F);
    const float4* r3 = (const float4*)(h1 + (size_t)(ibase + 3) * HID_F);
    float a0 = 0.f, a1 = 0.f, a2 = 0.f, a3 = 0.f;
#pragma unroll 4
    for (int k4 = 0; k4 < HID_F / 4; k4++) {
        float4 v0 = r0[k4], v1 = r1[k4], v2 = r2[k4], v3 = r3[k4];
        int k = k4 * 4;
        float w0 = Ws[(k + 0) * Z_F + j];
        float w1 = Ws[(k + 1) * Z_F + j];
        float w2 = Ws[(k + 2) * Z_F + j];
        float w3 = Ws[(k + 3) * Z_F + j];
        a0 += v0.x * w0 + v0.y * w1 + v0.z * w2 + v0.w * w3;
        a1 += v1.x * w0 + v1.y * w1 + v1.z * w2 + v1.w * w3;
        a2 += v2.x * w0 + v2.y * w1 + v2.z * w2 + v2.w * w3;
        a3 += v3.x * w0 + v3.y * w1 + v3.z * w2 + v3.w * w3;
    }
    t2s[(size_t)(ibase + 0) * Z_F + j] = f2bf(a0 * dinv[ibase + 0]);
    t2s[(size_t)(ibase + 1) * Z_F + j] = f2bf(a1 * dinv[ibase + 1]);
    t2s[(size_t)(ibase + 2) * Z_F + j] = f2bf(a2 * dinv[ibase + 2]);
    t2s[(size_t)(ibase + 3) * Z_F + j] = f2bf(a3 * dinv[ibase + 3]);
}

// ---------------- agg2: single pass, 64B rows, 8 edges/inst, unroll 2 ----------------
__global__ __launch_bounds__(256) void agg2_kernel(const unsigned short* __restrict__ t2s,
                                                   const int* __restrict__ rowptr,
                                                   const int* __restrict__ col,
                                                   const float* __restrict__ dinv,
                                                   const float* __restrict__ b2,
                                                   float* __restrict__ h2) {
    int lane = threadIdx.x & 63;
    int slot = lane >> 3;
    int fu = lane & 7;
    int i = blockIdx.x * 4 + (threadIdx.x >> 6);
    int s = rowptr[i], e = rowptr[i + 1];
    const uint2* t2v = (const uint2*)t2s;   // row stride 8 uint2
    float a0 = 0.f, a1 = 0.f, a2 = 0.f, a3 = 0.f;
    int p = s + slot;
    for (; p + 8 < e; p += 16) {
        int c0 = col[p], c1 = col[p + 8];
        uint2 u0 = t2v[(size_t)c0 * 8 + fu];
        uint2 u1 = t2v[(size_t)c1 * 8 + fu];
        a0 += bflo(u0.x) + bflo(u1.x);
        a1 += bfhi(u0.x) + bfhi(u1.x);
        a2 += bflo(u0.y) + bflo(u1.y);
        a3 += bfhi(u0.y) + bfhi(u1.y);
    }
    for (; p < e; p += 8) {
        uint2 u = t2v[(size_t)col[p] * 8 + fu];
        a0 += bflo(u.x); a1 += bfhi(u.x);
        a2 += bflo(u.y); a3 += bfhi(u.y);
    }
    a0 += __shfl_xor(a0, 8, 64);  a1 += __shfl_xor(a1, 8, 64);
    a2 += __shfl_xor(a2, 8, 64);  a3 += __shfl_xor(a3, 8, 64);
    a0 += __shfl_xor(a0, 16, 64); a1 += __shfl_xor(a1, 16, 64);
    a2 += __shfl_xor(a2, 16, 64); a3 += __shfl_xor(a3, 16, 64);
    a0 += __shfl_xor(a0, 32, 64); a1 += __shfl_xor(a1, 32, 64);
    a2 += __shfl_xor(a2, 32, 64); a3 += __shfl_xor(a3, 32, 64);
    if (slot == 0) {
        uint2 us = t2v[(size_t)i * 8 + fu];
        float di = dinv[i];
        float4 bb = ((const float4*)b2)[fu];
        float4 o;
        o.x = di * (a0 + bflo(us.x)) + bb.x;
        o.y = di * (a1 + bfhi(us.x)) + bb.y;
        o.z = di * (a2 + bflo(us.y)) + bb.z;
        o.w = di * (a3 + bfhi(us.y)) + bb.w;
        ((float4*)(h2 + (size_t)i * Z_F))[fu] = o;
    }
}

// ---------------- heads: mu = h2@Wmu+bmu, lv = h2@Wlv+blv ----------------
__global__ __launch_bounds__(256) void heads_kernel(const float* __restrict__ h2,
                                                    const float* __restrict__ Wmu,
                                                    const float* __restrict__ bmu,
                                                    const float* __restrict__ Wlv,
                                                    const float* __restrict__ blv,
                                                    float* __restrict__ out) {
    __shared__ float Wm[Z_F * Z_F], Wl[Z_F * Z_F], bm[Z_F], bl[Z_F];
    int tid = threadIdx.x;
    for (int k = tid; k < Z_F * Z_F; k += 256) {
        Wm[k] = Wmu[k];
        Wl[k] = Wlv[k];
    }
    if (tid < Z_F) {
        bm[tid] = bmu[tid];
        bl[tid] = blv[tid];
    }
    __syncthreads();
    int j = tid & 31;
    int nl = tid >> 5;
    int i = blockIdx.x * 8 + nl;   // 12500*8 = 100000 exact
    const float* hr = h2 + (size_t)i * Z_F;
    float am = bm[j], al = bl[j];
#pragma unroll 8
    for (int k = 0; k < Z_F; k++) {
        float hv = hr[k];
        am += hv * Wm[k * Z_F + j];
        al += hv * Wl[k * Z_F + j];
    }
    out[(size_t)i * Z_F + j] = am;
    out[(size_t)N_NODES * Z_F + (size_t)i * Z_F + j] = al;
}

extern "C" void kernel_launch(void* const* d_in, const int* in_sizes, int n_in,
                              void* d_out, int out_size, void* d_ws, size_t ws_size,
                              hipStream_t stream) {
    const float* x   = (const float*)d_in[0];
    const int*   ei  = (const int*)d_in[1];
    const float* W1  = (const float*)d_in[2];
    const float* b1  = (const float*)d_in[3];
    const float* W2  = (const float*)d_in[4];
    const float* b2  = (const float*)d_in[5];
    const float* Wmu = (const float*)d_in[6];
    const float* bmu = (const float*)d_in[7];
    const float* Wlv = (const float*)d_in[8];
    const float* blv = (const float*)d_in[9];
    float* out = (float*)d_out;

    char* ws = (char*)d_ws;
    size_t off = 0;
    auto A = [&](size_t bytes) {
        size_t r = off;
        off += (bytes + 255) & ~(size_t)255;
        return r;
    };
    int*   gcur       = (int*)(ws + A((size_t)NBUK * 4));
    int*   bucketBase = (int*)(ws + A((size_t)NBUK * 4));
    int*   rowptr     = (int*)(ws + A((size_t)(N_NODES + 1) * 4));
    float* dinv       = (float*)(ws + A((size_t)N_NODES * 4));
    int*   col        = (int*)(ws + A((size_t)N_EDGES * 4));                    // 6.4 MB
    char*  reg1 = ws + A((size_t)NBUK * BCAP * 4);                              // 9.6 MB: pairs -> t2s
    uint32* pairs = (uint32*)reg1;           // dead after phase2
    unsigned short* t2s = (unsigned short*)reg1;  // 6.4 MB, written by gemm2
    char*  reg2 = ws + A((size_t)N_NODES * HID_F * 2);                          // 12.8 MB: t1 -> h2
    unsigned short* t1 = (unsigned short*)reg2;   // dead after agg1
    float* h2 = (float*)reg2;                // written by agg2
    float* h1 = (float*)(ws + A((size_t)N_NODES * HID_F * 4));                  // 25.6 MB

    hipMemsetAsync(gcur, 0, (size_t)NBUK * 4, stream);

    phase1_kernel<<<P1_BLOCKS, 256, 0, stream>>>(ei, gcur, pairs);
    bucketscan_kernel<<<1, 1024, 0, stream>>>(gcur, bucketBase, rowptr);
    phase2_kernel<<<NBUK, 256, 0, stream>>>(pairs, gcur, bucketBase, rowptr, dinv, col);

    gemm1_kernel<<<(N_NODES + 63) / 64, 256, 0, stream>>>(x, W1, dinv, t1);
    agg1_kernel<<<N_NODES / 4, 256, 0, stream>>>(t1, rowptr, col, dinv, b1, h1);
    gemm2_kernel<<<N_NODES / 32, 256, 0, stream>>>(h1, W2, dinv, t2s);
    agg2_kernel<<<N_NODES / 4, 256, 0, stream>>>(t2s, rowptr, col, dinv, b2, h2);
    heads_kernel<<<N_NODES / 8, 256, 0, stream>>>(h2, Wmu, bmu, Wlv, blv, out);
}

// Round 7
// 240.459 us; speedup vs baseline: 5.1541x; 1.3639x over previous
//
#include <hip/hip_runtime.h>

#define N_NODES 100000
#define N_EDGES 1600000
#define IN_F   128
#define HID_F  64
#define Z_F    32
#define NBUK   782          // ceil(100000/128) buckets of 128 dst nodes
#define BCAP   3072         // bucket capacity (mean 2046, sigma ~45)
#define P1T    4096         // edges per phase1 block
#define P1_BLOCKS ((N_EDGES + P1T - 1) / P1T)   // 391
#define AGG_CAP 2048        // LDS col capacity per 64-node block (mean 1024, +32 sigma)

typedef unsigned int uint32;
typedef __attribute__((ext_vector_type(8))) short bf16x8;
typedef __attribute__((ext_vector_type(4))) float f32x4;

__device__ __forceinline__ unsigned short f2bf(float f) {
    unsigned u = __float_as_uint(f);
    u = (u + 0x7FFF + ((u >> 16) & 1)) >> 16;   // RNE
    return (unsigned short)u;
}
__device__ __forceinline__ float bflo(uint32 u) { return __uint_as_float(u << 16); }
__device__ __forceinline__ float bfhi(uint32 u) { return __uint_as_float(u & 0xFFFF0000u); }

// ---------------- phase 1: bucket partition with LDS-staged chunked writeback ----
__global__ __launch_bounds__(256) void phase1_kernel(const int* __restrict__ ei,
                                                     int* __restrict__ gcur,
                                                     uint32* __restrict__ pairs) {
    __shared__ int hist[NBUK];
    __shared__ int lbase[NBUK];
    __shared__ int gbase[NBUK];
    __shared__ int lcur[NBUK];
    __shared__ uint32 stage[P1T];
    __shared__ unsigned short sbid[P1T];
    __shared__ int part[256];
    int tid = threadIdx.x;
    int e0 = blockIdx.x * P1T;
    int ecnt = N_EDGES - e0; if (ecnt > P1T) ecnt = P1T;
    for (int b = tid; b < NBUK; b += 256) { hist[b] = 0; lcur[b] = 0; }
    __syncthreads();
    for (int k = tid; k < ecnt; k += 256)
        atomicAdd(&hist[ei[N_EDGES + e0 + k] >> 7], 1);
    __syncthreads();
    int t4 = tid * 4;
    int l0 = 0, l1 = 0, l2 = 0, l3 = 0, s = 0;
    if (t4 + 0 < NBUK) { l0 = hist[t4 + 0]; s += l0; }
    if (t4 + 1 < NBUK) { l1 = hist[t4 + 1]; s += l1; }
    if (t4 + 2 < NBUK) { l2 = hist[t4 + 2]; s += l2; }
    if (t4 + 3 < NBUK) { l3 = hist[t4 + 3]; s += l3; }
    part[tid] = s;
    __syncthreads();
    for (int off = 1; off < 256; off <<= 1) {
        int add = (tid >= off) ? part[tid - off] : 0;
        __syncthreads();
        part[tid] += add;
        __syncthreads();
    }
    int run = part[tid] - s;
    if (t4 + 0 < NBUK) { lbase[t4 + 0] = run; run += l0; }
    if (t4 + 1 < NBUK) { lbase[t4 + 1] = run; run += l1; }
    if (t4 + 2 < NBUK) { lbase[t4 + 2] = run; run += l2; }
    if (t4 + 3 < NBUK) { lbase[t4 + 3] = run; run += l3; }
    for (int b = tid; b < NBUK; b += 256) {
        int h = hist[b];
        gbase[b] = h ? atomicAdd(&gcur[b], h) : 0;
    }
    __syncthreads();
    for (int k = tid; k < ecnt; k += 256) {
        int sN = ei[e0 + k];
        int d  = ei[N_EDGES + e0 + k];
        int b = d >> 7;
        int slot = lbase[b] + atomicAdd(&lcur[b], 1);
        stage[slot] = (uint32)sN | ((uint32)(d & 127) << 17);
        sbid[slot] = (unsigned short)b;
    }
    __syncthreads();
    for (int k = tid; k < ecnt; k += 256) {
        int b = sbid[k];
        int r = gbase[b] + (k - lbase[b]);
        if (r < BCAP) pairs[(size_t)b * BCAP + r] = stage[k];
    }
}

// ---------------- prep: bucket scan + weight transpose/convert to bf16 ----------
__global__ void prep_kernel(const int* __restrict__ gcur,
                            const float* __restrict__ W1, const float* __restrict__ W2,
                            const float* __restrict__ Wmu, const float* __restrict__ Wlv,
                            int* __restrict__ bucketBase, int* __restrict__ rowptr,
                            unsigned short* __restrict__ Wt1,
                            unsigned short* __restrict__ Wt2,
                            unsigned short* __restrict__ Wth) {
    __shared__ int s[1024];
    int t = threadIdx.x;
    int v = (t < NBUK) ? gcur[t] : 0;
    s[t] = v;
    __syncthreads();
    for (int off = 1; off < 1024; off <<= 1) {
        int add = (t >= off) ? s[t - off] : 0;
        __syncthreads();
        s[t] += add;
        __syncthreads();
    }
    if (t < NBUK) bucketBase[t] = s[t] - v;
    if (t == 0) rowptr[N_NODES] = N_EDGES;
    for (int i = t; i < IN_F * HID_F; i += 1024) {           // Wt1[n][k] = W1[k][n]
        int n = i >> 7, k = i & 127;
        Wt1[i] = f2bf(W1[k * HID_F + n]);
    }
    for (int i = t; i < HID_F * Z_F; i += 1024) {            // Wt2[n][k] = W2[k][n]
        int n = i >> 6, k = i & 63;
        Wt2[i] = f2bf(W2[k * Z_F + n]);
    }
    for (int i = t; i < Z_F * 64; i += 1024) {               // Wth[n][k]: n<32 mu, else lv
        int n = i >> 5, k = i & 31;
        Wth[i] = f2bf(n < 32 ? Wmu[k * Z_F + n] : Wlv[k * Z_F + (n - 32)]);
    }
}

// ---------------- phase 2: per-bucket CSR build (coalesced writes, LDS scatter) ----
__global__ __launch_bounds__(256) void phase2_kernel(const uint32* __restrict__ pairs,
                                                     const int* __restrict__ gcur,
                                                     const int* __restrict__ bucketBase,
                                                     int* __restrict__ rowptr,
                                                     float* __restrict__ dinv,
                                                     int* __restrict__ col) {
    __shared__ int lhist[128];
    __shared__ int lscan[128];
    __shared__ int lcur[128];
    __shared__ int stage[BCAP];
    int b = blockIdx.x;
    int tid = threadIdx.x;
    int cnt_b = gcur[b];
    if (cnt_b > BCAP) cnt_b = BCAP;
    int gbase = bucketBase[b];
    int node0 = b << 7;
    int nb = N_NODES - node0;
    if (nb > 128) nb = 128;
    if (tid < 128) { lhist[tid] = 0; lcur[tid] = 0; }
    __syncthreads();
    const uint32* pb = pairs + (size_t)b * BCAP;
    for (int k = tid; k < cnt_b; k += 256) atomicAdd(&lhist[pb[k] >> 17], 1);
    __syncthreads();
    int v = (tid < 128) ? lhist[tid] : 0;
    if (tid < 128) lscan[tid] = v;
    __syncthreads();
    for (int off = 1; off < 128; off <<= 1) {
        int add = (tid < 128 && tid >= off) ? lscan[tid - off] : 0;
        __syncthreads();
        if (tid < 128) lscan[tid] += add;
        __syncthreads();
    }
    if (tid < 128) lscan[tid] -= v;  // exclusive
    __syncthreads();
    if (tid < nb) {
        rowptr[node0 + tid] = gbase + lscan[tid];
        dinv[node0 + tid] = rsqrtf((float)(lhist[tid] + 1));
    }
    for (int k = tid; k < cnt_b; k += 256) {
        uint32 u = pb[k];
        int ld = u >> 17;
        int r = atomicAdd(&lcur[ld], 1);
        stage[lscan[ld] + r] = (int)(u & 0x1FFFF);
    }
    __syncthreads();
    for (int k = tid; k < cnt_b; k += 256) col[gbase + k] = stage[k];
}

// ---------------- GEMM1 (MFMA, LDS-free A/B): t1 = bf16(dinv * (x@W1)) [N,64] -----
__global__ __launch_bounds__(256) void gemm1_kernel(const float* __restrict__ x,
                                                    const unsigned short* __restrict__ Wt1,
                                                    const float* __restrict__ dinv,
                                                    unsigned short* __restrict__ t1) {
    __shared__ unsigned short Cs[64 * 72];
    __shared__ float dv[64];
    int tid = threadIdx.x;
    int node0 = blockIdx.x * 64;
    if (tid < 64) {
        int n = node0 + tid;
        dv[tid] = (n < N_NODES) ? dinv[n] : 0.f;
    }
    __syncthreads();
    int w = tid >> 6, lane = tid & 63;
    int m = lane & 15, quad = lane >> 4;
    int row = w * 16 + m;
    int node = node0 + row;
    const float* xr = x + (size_t)min(node, N_NODES - 1) * IN_F;
    f32x4 acc0 = {0.f, 0.f, 0.f, 0.f};
    f32x4 acc1 = acc0, acc2 = acc0, acc3 = acc0;
#pragma unroll
    for (int ks = 0; ks < 4; ks++) {
        int kb = ks * 32 + quad * 8;
        float4 f0 = *(const float4*)(xr + kb);
        float4 f1 = *(const float4*)(xr + kb + 4);
        union { bf16x8 v; unsigned short u[8]; } A;
        A.u[0] = f2bf(f0.x); A.u[1] = f2bf(f0.y); A.u[2] = f2bf(f0.z); A.u[3] = f2bf(f0.w);
        A.u[4] = f2bf(f1.x); A.u[5] = f2bf(f1.y); A.u[6] = f2bf(f1.z); A.u[7] = f2bf(f1.w);
        bf16x8 b0 = *(const bf16x8*)&Wt1[(0 * 16 + m) * IN_F + kb];
        bf16x8 b1 = *(const bf16x8*)&Wt1[(1 * 16 + m) * IN_F + kb];
        bf16x8 b2 = *(const bf16x8*)&Wt1[(2 * 16 + m) * IN_F + kb];
        bf16x8 b3 = *(const bf16x8*)&Wt1[(3 * 16 + m) * IN_F + kb];
        acc0 = __builtin_amdgcn_mfma_f32_16x16x32_bf16(A.v, b0, acc0, 0, 0, 0);
        acc1 = __builtin_amdgcn_mfma_f32_16x16x32_bf16(A.v, b1, acc1, 0, 0, 0);
        acc2 = __builtin_amdgcn_mfma_f32_16x16x32_bf16(A.v, b2, acc2, 0, 0, 0);
        acc3 = __builtin_amdgcn_mfma_f32_16x16x32_bf16(A.v, b3, acc3, 0, 0, 0);
    }
    int rbase = w * 16 + quad * 4;
#pragma unroll
    for (int reg = 0; reg < 4; reg++) {
        int r = rbase + reg;
        float d = dv[r];
        Cs[r * 72 +  0 + m] = f2bf(acc0[reg] * d);
        Cs[r * 72 + 16 + m] = f2bf(acc1[reg] * d);
        Cs[r * 72 + 32 + m] = f2bf(acc2[reg] * d);
        Cs[r * 72 + 48 + m] = f2bf(acc3[reg] * d);
    }
    __syncthreads();
#pragma unroll
    for (int it = 0; it < 4; it++) {
        int idx = it * 256 + tid;
        int r = idx >> 4, c = idx & 15;
        int nd = node0 + r;
        if (nd < N_NODES) {
            uint2 vv = *(const uint2*)&Cs[r * 72 + c * 4];
            *(uint2*)&t1[(size_t)nd * HID_F + c * 4] = vv;
        }
    }
}

// ---------------- agg1: block = 64 dst nodes; LDS col staging; quarter = node -----
__global__ __launch_bounds__(256) void agg1_kernel(const unsigned short* __restrict__ t1,
                                                   const int* __restrict__ rowptr,
                                                   const int* __restrict__ col,
                                                   const float* __restrict__ dinv,
                                                   const float* __restrict__ b1,
                                                   float* __restrict__ h1) {
    __shared__ int lcol[AGG_CAP];
    __shared__ int lrp[65];
    __shared__ float ldv[64];
    int tid = threadIdx.x;
    int node0 = blockIdx.x * 64;
    if (tid < 65) lrp[tid] = rowptr[min(node0 + tid, N_NODES)];
    __syncthreads();
    int s0 = lrp[0];
    int cnt = lrp[64] - s0; if (cnt > AGG_CAP) cnt = AGG_CAP;
    for (int k = tid; k < cnt; k += 256) lcol[k] = col[s0 + k];
    if (tid < 64) {
        int n = node0 + tid;
        ldv[tid] = (n < N_NODES) ? dinv[n] : 0.f;
    }
    __syncthreads();
    int lane = tid & 63, w = tid >> 6;
    int q = lane >> 4, fl = lane & 15;
    int qg = w * 4 + q;                    // 0..15
    const uint2* t1v = (const uint2*)t1;   // row stride 16 uint2
    float4 bb = ((const float4*)b1)[fl];
#pragma unroll
    for (int rep = 0; rep < 4; rep++) {
        int li = qg + rep * 16;
        int node = node0 + li;
        if (node >= N_NODES) break;
        int s = lrp[li] - s0;
        int e = lrp[li + 1] - s0; if (e > cnt) e = cnt;
        float a0 = 0.f, a1 = 0.f, a2 = 0.f, a3 = 0.f;
        int p = s;
        for (; p + 3 < e; p += 4) {
            int c0 = lcol[p], c1 = lcol[p + 1], c2 = lcol[p + 2], c3 = lcol[p + 3];
            uint2 u0 = t1v[(size_t)c0 * 16 + fl];
            uint2 u1 = t1v[(size_t)c1 * 16 + fl];
            uint2 u2 = t1v[(size_t)c2 * 16 + fl];
            uint2 u3 = t1v[(size_t)c3 * 16 + fl];
            a0 += bflo(u0.x) + bflo(u1.x) + bflo(u2.x) + bflo(u3.x);
            a1 += bfhi(u0.x) + bfhi(u1.x) + bfhi(u2.x) + bfhi(u3.x);
            a2 += bflo(u0.y) + bflo(u1.y) + bflo(u2.y) + bflo(u3.y);
            a3 += bfhi(u0.y) + bfhi(u1.y) + bfhi(u2.y) + bfhi(u3.y);
        }
        for (; p < e; p++) {
            uint2 u = t1v[(size_t)lcol[p] * 16 + fl];
            a0 += bflo(u.x); a1 += bfhi(u.x);
            a2 += bflo(u.y); a3 += bfhi(u.y);
        }
        uint2 us = t1v[(size_t)node * 16 + fl];
        float di = ldv[li];
        float4 o;
        o.x = fmaxf(di * (a0 + bflo(us.x)) + bb.x, 0.f);
        o.y = fmaxf(di * (a1 + bfhi(us.x)) + bb.y, 0.f);
        o.z = fmaxf(di * (a2 + bflo(us.y)) + bb.z, 0.f);
        o.w = fmaxf(di * (a3 + bfhi(us.y)) + bb.w, 0.f);
        ((float4*)(h1 + (size_t)node * HID_F))[fl] = o;
    }
}

// ---------------- GEMM2 (MFMA, LDS-free): t2s = bf16(dinv * (h1@W2)) [N,32] -------
__global__ __launch_bounds__(256) void gemm2_kernel(const float* __restrict__ h1,
                                                    const unsigned short* __restrict__ Wt2,
                                                    const float* __restrict__ dinv,
                                                    unsigned short* __restrict__ t2s) {
    __shared__ unsigned short Cs[64 * 36];
    __shared__ float dv[64];
    int tid = threadIdx.x;
    int node0 = blockIdx.x * 64;
    if (tid < 64) {
        int n = node0 + tid;
        dv[tid] = (n < N_NODES) ? dinv[n] : 0.f;
    }
    __syncthreads();
    int w = tid >> 6, lane = tid & 63;
    int m = lane & 15, quad = lane >> 4;
    int node = node0 + w * 16 + m;
    const float* hr = h1 + (size_t)min(node, N_NODES - 1) * HID_F;
    f32x4 acc0 = {0.f, 0.f, 0.f, 0.f};
    f32x4 acc1 = acc0;
#pragma unroll
    for (int ks = 0; ks < 2; ks++) {
        int kb = ks * 32 + quad * 8;
        float4 f0 = *(const float4*)(hr + kb);
        float4 f1 = *(const float4*)(hr + kb + 4);
        union { bf16x8 v; unsigned short u[8]; } A;
        A.u[0] = f2bf(f0.x); A.u[1] = f2bf(f0.y); A.u[2] = f2bf(f0.z); A.u[3] = f2bf(f0.w);
        A.u[4] = f2bf(f1.x); A.u[5] = f2bf(f1.y); A.u[6] = f2bf(f1.z); A.u[7] = f2bf(f1.w);
        bf16x8 b0 = *(const bf16x8*)&Wt2[(0 * 16 + m) * HID_F + kb];
        bf16x8 b1 = *(const bf16x8*)&Wt2[(1 * 16 + m) * HID_F + kb];
        acc0 = __builtin_amdgcn_mfma_f32_16x16x32_bf16(A.v, b0, acc0, 0, 0, 0);
        acc1 = __builtin_amdgcn_mfma_f32_16x16x32_bf16(A.v, b1, acc1, 0, 0, 0);
    }
    int rbase = w * 16 + quad * 4;
#pragma unroll
    for (int reg = 0; reg < 4; reg++) {
        int r = rbase + reg;
        float d = dv[r];
        Cs[r * 36 +  0 + m] = f2bf(acc0[reg] * d);
        Cs[r * 36 + 16 + m] = f2bf(acc1[reg] * d);
    }
    __syncthreads();
#pragma unroll
    for (int it = 0; it < 2; it++) {
        int idx = it * 256 + tid;
        int r = idx >> 3, c = idx & 7;
        int nd = node0 + r;
        if (nd < N_NODES) {
            uint2 vv = *(const uint2*)&Cs[r * 36 + c * 4];
            *(uint2*)&t2s[(size_t)nd * Z_F + c * 4] = vv;
        }
    }
}

// ---------------- agg2: block = 64 dst nodes; octet = node -----------------------
__global__ __launch_bounds__(256) void agg2_kernel(const unsigned short* __restrict__ t2s,
                                                   const int* __restrict__ rowptr,
                                                   const int* __restrict__ col,
                                                   const float* __restrict__ dinv,
                                                   const float* __restrict__ b2,
                                                   float* __restrict__ h2) {
    __shared__ int lcol[AGG_CAP];
    __shared__ int lrp[65];
    __shared__ float ldv[64];
    int tid = threadIdx.x;
    int node0 = blockIdx.x * 64;
    if (tid < 65) lrp[tid] = rowptr[min(node0 + tid, N_NODES)];
    __syncthreads();
    int s0 = lrp[0];
    int cnt = lrp[64] - s0; if (cnt > AGG_CAP) cnt = AGG_CAP;
    for (int k = tid; k < cnt; k += 256) lcol[k] = col[s0 + k];
    if (tid < 64) {
        int n = node0 + tid;
        ldv[tid] = (n < N_NODES) ? dinv[n] : 0.f;
    }
    __syncthreads();
    int lane = tid & 63, w = tid >> 6;
    int oc = lane >> 3, fo = lane & 7;
    int og = w * 8 + oc;                   // 0..31
    const uint2* t2v = (const uint2*)t2s;  // row stride 8 uint2
    float4 bb = ((const float4*)b2)[fo];
#pragma unroll
    for (int rep = 0; rep < 2; rep++) {
        int li = og + rep * 32;
        int node = node0 + li;
        if (node >= N_NODES) break;
        int s = lrp[li] - s0;
        int e = lrp[li + 1] - s0; if (e > cnt) e = cnt;
        float a0 = 0.f, a1 = 0.f, a2 = 0.f, a3 = 0.f;
        int p = s;
        for (; p + 3 < e; p += 4) {
            int c0 = lcol[p], c1 = lcol[p + 1], c2 = lcol[p + 2], c3 = lcol[p + 3];
            uint2 u0 = t2v[(size_t)c0 * 8 + fo];
            uint2 u1 = t2v[(size_t)c1 * 8 + fo];
            uint2 u2 = t2v[(size_t)c2 * 8 + fo];
            uint2 u3 = t2v[(size_t)c3 * 8 + fo];
            a0 += bflo(u0.x) + bflo(u1.x) + bflo(u2.x) + bflo(u3.x);
            a1 += bfhi(u0.x) + bfhi(u1.x) + bfhi(u2.x) + bfhi(u3.x);
            a2 += bflo(u0.y) + bflo(u1.y) + bflo(u2.y) + bflo(u3.y);
            a3 += bfhi(u0.y) + bfhi(u1.y) + bfhi(u2.y) + bfhi(u3.y);
        }
        for (; p < e; p++) {
            uint2 u = t2v[(size_t)lcol[p] * 8 + fo];
            a0 += bflo(u.x); a1 += bfhi(u.x);
            a2 += bflo(u.y); a3 += bfhi(u.y);
        }
        uint2 us = t2v[(size_t)node * 8 + fo];
        float di = ldv[li];
        float4 o;
        o.x = di * (a0 + bflo(us.x)) + bb.x;
        o.y = di * (a1 + bfhi(us.x)) + bb.y;
        o.z = di * (a2 + bflo(us.y)) + bb.z;
        o.w = di * (a3 + bfhi(us.y)) + bb.w;
        ((float4*)(h2 + (size_t)node * Z_F))[fo] = o;
    }
}

// ---------------- heads (MFMA): [mu|lv] = h2 @ Wth + [bmu|blv] --------------------
__global__ __launch_bounds__(256) void heads_kernel(const float* __restrict__ h2,
                                                    const unsigned short* __restrict__ Wth,
                                                    const float* __restrict__ bmu,
                                                    const float* __restrict__ blv,
                                                    float* __restrict__ out) {
    __shared__ float Cf[64 * 68];
    __shared__ float bias[64];
    int tid = threadIdx.x;
    int node0 = blockIdx.x * 64;
    if (tid < 32) bias[tid] = bmu[tid];
    else if (tid < 64) bias[tid] = blv[tid - 32];
    __syncthreads();
    int w = tid >> 6, lane = tid & 63;
    int m = lane & 15, quad = lane >> 4;
    int node = node0 + w * 16 + m;
    const float* hr = h2 + (size_t)min(node, N_NODES - 1) * Z_F;
    int kb = quad * 8;
    float4 f0 = *(const float4*)(hr + kb);
    float4 f1 = *(const float4*)(hr + kb + 4);
    union { bf16x8 v; unsigned short u[8]; } A;
    A.u[0] = f2bf(f0.x); A.u[1] = f2bf(f0.y); A.u[2] = f2bf(f0.z); A.u[3] = f2bf(f0.w);
    A.u[4] = f2bf(f1.x); A.u[5] = f2bf(f1.y); A.u[6] = f2bf(f1.z); A.u[7] = f2bf(f1.w);
    f32x4 acc0 = {0.f, 0.f, 0.f, 0.f};
    f32x4 acc1 = acc0, acc2 = acc0, acc3 = acc0;
    bf16x8 b0 = *(const bf16x8*)&Wth[(0 * 16 + m) * Z_F + kb];
    bf16x8 b1 = *(const bf16x8*)&Wth[(1 * 16 + m) * Z_F + kb];
    bf16x8 b2 = *(const bf16x8*)&Wth[(2 * 16 + m) * Z_F + kb];
    bf16x8 b3 = *(const bf16x8*)&Wth[(3 * 16 + m) * Z_F + kb];
    acc0 = __builtin_amdgcn_mfma_f32_16x16x32_bf16(A.v, b0, acc0, 0, 0, 0);
    acc1 = __builtin_amdgcn_mfma_f32_16x16x32_bf16(A.v, b1, acc1, 0, 0, 0);
    acc2 = __builtin_amdgcn_mfma_f32_16x16x32_bf16(A.v, b2, acc2, 0, 0, 0);
    acc3 = __builtin_amdgcn_mfma_f32_16x16x32_bf16(A.v, b3, acc3, 0, 0, 0);
    int rbase = w * 16 + quad * 4;
#pragma unroll
    for (int reg = 0; reg < 4; reg++) {
        int r = rbase + reg;
        Cf[r * 68 +  0 + m] = acc0[reg] + bias[ 0 + m];
        Cf[r * 68 + 16 + m] = acc1[reg] + bias[16 + m];
        Cf[r * 68 + 32 + m] = acc2[reg] + bias[32 + m];
        Cf[r * 68 + 48 + m] = acc3[reg] + bias[48 + m];
    }
    __syncthreads();
#pragma unroll
    for (int it = 0; it < 2; it++) {
        int idx = it * 256 + tid;
        int r = idx >> 3, c = idx & 7;
        int nd = node0 + r;
        if (nd < N_NODES) {
            float4 vmu = *(const float4*)&Cf[r * 68 + c * 4];
            float4 vlv = *(const float4*)&Cf[r * 68 + 32 + c * 4];
            *(float4*)&out[(size_t)nd * Z_F + c * 4] = vmu;
            *(float4*)&out[(size_t)N_NODES * Z_F + (size_t)nd * Z_F + c * 4] = vlv;
        }
    }
}

extern "C" void kernel_launch(void* const* d_in, const int* in_sizes, int n_in,
                              void* d_out, int out_size, void* d_ws, size_t ws_size,
                              hipStream_t stream) {
    const float* x   = (const float*)d_in[0];
    const int*   ei  = (const int*)d_in[1];
    const float* W1  = (const float*)d_in[2];
    const float* b1  = (const float*)d_in[3];
    const float* W2  = (const float*)d_in[4];
    const float* b2  = (const float*)d_in[5];
    const float* Wmu = (const float*)d_in[6];
    const float* bmu = (const float*)d_in[7];
    const float* Wlv = (const float*)d_in[8];
    const float* blv = (const float*)d_in[9];
    float* out = (float*)d_out;

    char* ws = (char*)d_ws;
    size_t off = 0;
    auto A = [&](size_t bytes) {
        size_t r = off;
        off += (bytes + 255) & ~(size_t)255;
        return r;
    };
    int*   gcur       = (int*)(ws + A((size_t)NBUK * 4));
    int*   bucketBase = (int*)(ws + A((size_t)NBUK * 4));
    int*   rowptr     = (int*)(ws + A((size_t)(N_NODES + 1) * 4));
    float* dinv       = (float*)(ws + A((size_t)N_NODES * 4));
    unsigned short* Wt1 = (unsigned short*)(ws + A((size_t)IN_F * HID_F * 2));
    unsigned short* Wt2 = (unsigned short*)(ws + A((size_t)HID_F * Z_F * 2));
    unsigned short* Wth = (unsigned short*)(ws + A((size_t)Z_F * 64 * 2));
    int*   col        = (int*)(ws + A((size_t)N_EDGES * 4));                    // 6.4 MB
    char*  reg1 = ws + A((size_t)NBUK * BCAP * 4);                              // 9.6 MB: pairs -> t2s
    uint32* pairs = (uint32*)reg1;                // dead after phase2
    unsigned short* t2s = (unsigned short*)reg1;  // 6.4 MB, written by gemm2
    char*  reg2 = ws + A((size_t)N_NODES * HID_F * 2);                          // 12.8 MB: t1 -> h2
    unsigned short* t1 = (unsigned short*)reg2;   // dead after agg1
    float* h2 = (float*)reg2;                     // written by agg2
    float* h1 = (float*)(ws + A((size_t)N_NODES * HID_F * 4));                  // 25.6 MB

    hipMemsetAsync(gcur, 0, (size_t)NBUK * 4, stream);

    phase1_kernel<<<P1_BLOCKS, 256, 0, stream>>>(ei, gcur, pairs);
    prep_kernel<<<1, 1024, 0, stream>>>(gcur, W1, W2, Wmu, Wlv, bucketBase, rowptr,
                                        Wt1, Wt2, Wth);
    phase2_kernel<<<NBUK, 256, 0, stream>>>(pairs, gcur, bucketBase, rowptr, dinv, col);

    int nblk = (N_NODES + 63) / 64;   // 1563
    gemm1_kernel<<<nblk, 256, 0, stream>>>(x, Wt1, dinv, t1);
    agg1_kernel<<<nblk, 256, 0, stream>>>(t1, rowptr, col, dinv, b1, h1);
    gemm2_kernel<<<nblk, 256, 0, stream>>>(h1, Wt2, dinv, t2s);
    agg2_kernel<<<nblk, 256, 0, stream>>>(t2s, rowptr, col, dinv, b2, h2);
    heads_kernel<<<nblk, 256, 0, stream>>>(h2, Wth, bmu, blv, out);
}

// Round 8
// 228.188 us; speedup vs baseline: 5.4312x; 1.0538x over previous
//
#include <hip/hip_runtime.h>

#define N_NODES 100000
#define N_EDGES 1600000
#define IN_F   128
#define HID_F  64
#define Z_F    32
#define NBUK   782          // ceil(100000/128) buckets of 128 dst nodes
#define BCAP   3072         // bucket capacity (mean 2046, sigma ~45)
#define P1T    4096         // edges per phase1 block
#define P1_BLOCKS ((N_EDGES + P1T - 1) / P1T)   // 391
#define AGG_CAP 2048        // LDS col capacity per 64-node block (mean 1024, +32 sigma)

typedef unsigned int uint32;
typedef __attribute__((ext_vector_type(8))) short bf16x8;
typedef __attribute__((ext_vector_type(4))) float f32x4;

__device__ __forceinline__ unsigned short f2bf(float f) {
    unsigned u = __float_as_uint(f);
    u = (u + 0x7FFF + ((u >> 16) & 1)) >> 16;   // RNE
    return (unsigned short)u;
}
__device__ __forceinline__ uint32 pack2bf(float lo, float hi) {
    return (uint32)f2bf(lo) | ((uint32)f2bf(hi) << 16);
}
__device__ __forceinline__ float bflo(uint32 u) { return __uint_as_float(u << 16); }
__device__ __forceinline__ float bfhi(uint32 u) { return __uint_as_float(u & 0xFFFF0000u); }

// ---------------- phase 1: bucket partition with LDS-staged chunked writeback ----
__global__ __launch_bounds__(256) void phase1_kernel(const int* __restrict__ ei,
                                                     int* __restrict__ gcur,
                                                     uint32* __restrict__ pairs) {
    __shared__ int hist[NBUK];
    __shared__ int lbase[NBUK];
    __shared__ int gbase[NBUK];
    __shared__ int lcur[NBUK];
    __shared__ uint32 stage[P1T];
    __shared__ unsigned short sbid[P1T];
    __shared__ int part[256];
    int tid = threadIdx.x;
    int e0 = blockIdx.x * P1T;
    int ecnt = N_EDGES - e0; if (ecnt > P1T) ecnt = P1T;
    for (int b = tid; b < NBUK; b += 256) { hist[b] = 0; lcur[b] = 0; }
    __syncthreads();
    for (int k = tid; k < ecnt; k += 256)
        atomicAdd(&hist[ei[N_EDGES + e0 + k] >> 7], 1);
    __syncthreads();
    int t4 = tid * 4;
    int l0 = 0, l1 = 0, l2 = 0, l3 = 0, s = 0;
    if (t4 + 0 < NBUK) { l0 = hist[t4 + 0]; s += l0; }
    if (t4 + 1 < NBUK) { l1 = hist[t4 + 1]; s += l1; }
    if (t4 + 2 < NBUK) { l2 = hist[t4 + 2]; s += l2; }
    if (t4 + 3 < NBUK) { l3 = hist[t4 + 3]; s += l3; }
    part[tid] = s;
    __syncthreads();
    for (int off = 1; off < 256; off <<= 1) {
        int add = (tid >= off) ? part[tid - off] : 0;
        __syncthreads();
        part[tid] += add;
        __syncthreads();
    }
    int run = part[tid] - s;
    if (t4 + 0 < NBUK) { lbase[t4 + 0] = run; run += l0; }
    if (t4 + 1 < NBUK) { lbase[t4 + 1] = run; run += l1; }
    if (t4 + 2 < NBUK) { lbase[t4 + 2] = run; run += l2; }
    if (t4 + 3 < NBUK) { lbase[t4 + 3] = run; run += l3; }
    for (int b = tid; b < NBUK; b += 256) {
        int h = hist[b];
        gbase[b] = h ? atomicAdd(&gcur[b], h) : 0;
    }
    __syncthreads();
    for (int k = tid; k < ecnt; k += 256) {
        int sN = ei[e0 + k];
        int d  = ei[N_EDGES + e0 + k];
        int b = d >> 7;
        int slot = lbase[b] + atomicAdd(&lcur[b], 1);
        stage[slot] = (uint32)sN | ((uint32)(d & 127) << 17);
        sbid[slot] = (unsigned short)b;
    }
    __syncthreads();
    for (int k = tid; k < ecnt; k += 256) {
        int b = sbid[k];
        int r = gbase[b] + (k - lbase[b]);
        if (r < BCAP) pairs[(size_t)b * BCAP + r] = stage[k];
    }
}

// ---------------- prep: bucket scan + weight transpose/convert to bf16 ----------
__global__ void prep_kernel(const int* __restrict__ gcur,
                            const float* __restrict__ W1, const float* __restrict__ W2,
                            const float* __restrict__ Wmu, const float* __restrict__ Wlv,
                            int* __restrict__ bucketBase, int* __restrict__ rowptr,
                            unsigned short* __restrict__ Wt1,
                            unsigned short* __restrict__ Wt2,
                            unsigned short* __restrict__ Wth) {
    __shared__ int s[1024];
    int t = threadIdx.x;
    int v = (t < NBUK) ? gcur[t] : 0;
    s[t] = v;
    __syncthreads();
    for (int off = 1; off < 1024; off <<= 1) {
        int add = (t >= off) ? s[t - off] : 0;
        __syncthreads();
        s[t] += add;
        __syncthreads();
    }
    if (t < NBUK) bucketBase[t] = s[t] - v;
    if (t == 0) rowptr[N_NODES] = N_EDGES;
    for (int i = t; i < IN_F * HID_F; i += 1024) {           // Wt1[n][k] = W1[k][n]
        int n = i >> 7, k = i & 127;
        Wt1[i] = f2bf(W1[k * HID_F + n]);
    }
    for (int i = t; i < HID_F * Z_F; i += 1024) {            // Wt2[n][k] = W2[k][n]
        int n = i >> 6, k = i & 63;
        Wt2[i] = f2bf(W2[k * Z_F + n]);
    }
    for (int i = t; i < Z_F * 64; i += 1024) {               // Wth[n][k]: n<32 mu, else lv
        int n = i >> 5, k = i & 31;
        Wth[i] = f2bf(n < 32 ? Wmu[k * Z_F + n] : Wlv[k * Z_F + (n - 32)]);
    }
}

// ---------------- phase 2: per-bucket CSR build (coalesced writes, LDS scatter) ----
__global__ __launch_bounds__(256) void phase2_kernel(const uint32* __restrict__ pairs,
                                                     const int* __restrict__ gcur,
                                                     const int* __restrict__ bucketBase,
                                                     int* __restrict__ rowptr,
                                                     float* __restrict__ dinv,
                                                     int* __restrict__ col) {
    __shared__ int lhist[128];
    __shared__ int lscan[128];
    __shared__ int lcur[128];
    __shared__ int stage[BCAP];
    int b = blockIdx.x;
    int tid = threadIdx.x;
    int cnt_b = gcur[b];
    if (cnt_b > BCAP) cnt_b = BCAP;
    int gbase = bucketBase[b];
    int node0 = b << 7;
    int nb = N_NODES - node0;
    if (nb > 128) nb = 128;
    if (tid < 128) { lhist[tid] = 0; lcur[tid] = 0; }
    __syncthreads();
    const uint32* pb = pairs + (size_t)b * BCAP;
    for (int k = tid; k < cnt_b; k += 256) atomicAdd(&lhist[pb[k] >> 17], 1);
    __syncthreads();
    int v = (tid < 128) ? lhist[tid] : 0;
    if (tid < 128) lscan[tid] = v;
    __syncthreads();
    for (int off = 1; off < 128; off <<= 1) {
        int add = (tid < 128 && tid >= off) ? lscan[tid - off] : 0;
        __syncthreads();
        if (tid < 128) lscan[tid] += add;
        __syncthreads();
    }
    if (tid < 128) lscan[tid] -= v;  // exclusive
    __syncthreads();
    if (tid < nb) {
        rowptr[node0 + tid] = gbase + lscan[tid];
        dinv[node0 + tid] = rsqrtf((float)(lhist[tid] + 1));
    }
    for (int k = tid; k < cnt_b; k += 256) {
        uint32 u = pb[k];
        int ld = u >> 17;
        int r = atomicAdd(&lcur[ld], 1);
        stage[lscan[ld] + r] = (int)(u & 0x1FFFF);
    }
    __syncthreads();
    for (int k = tid; k < cnt_b; k += 256) col[gbase + k] = stage[k];
}

// ---------------- GEMM1 (MFMA, LDS-free A/B): t1 = bf16(dinv * (x@W1)) [N,64] -----
__global__ __launch_bounds__(256) void gemm1_kernel(const float* __restrict__ x,
                                                    const unsigned short* __restrict__ Wt1,
                                                    const float* __restrict__ dinv,
                                                    unsigned short* __restrict__ t1) {
    __shared__ unsigned short Cs[64 * 72];
    __shared__ float dv[64];
    int tid = threadIdx.x;
    int node0 = blockIdx.x * 64;
    if (tid < 64) {
        int n = node0 + tid;
        dv[tid] = (n < N_NODES) ? dinv[n] : 0.f;
    }
    __syncthreads();
    int w = tid >> 6, lane = tid & 63;
    int m = lane & 15, quad = lane >> 4;
    int row = w * 16 + m;
    int node = node0 + row;
    const float* xr = x + (size_t)min(node, N_NODES - 1) * IN_F;
    f32x4 acc0 = {0.f, 0.f, 0.f, 0.f};
    f32x4 acc1 = acc0, acc2 = acc0, acc3 = acc0;
#pragma unroll
    for (int ks = 0; ks < 4; ks++) {
        int kb = ks * 32 + quad * 8;
        float4 f0 = *(const float4*)(xr + kb);
        float4 f1 = *(const float4*)(xr + kb + 4);
        union { bf16x8 v; unsigned short u[8]; } A;
        A.u[0] = f2bf(f0.x); A.u[1] = f2bf(f0.y); A.u[2] = f2bf(f0.z); A.u[3] = f2bf(f0.w);
        A.u[4] = f2bf(f1.x); A.u[5] = f2bf(f1.y); A.u[6] = f2bf(f1.z); A.u[7] = f2bf(f1.w);
        bf16x8 b0 = *(const bf16x8*)&Wt1[(0 * 16 + m) * IN_F + kb];
        bf16x8 b1 = *(const bf16x8*)&Wt1[(1 * 16 + m) * IN_F + kb];
        bf16x8 b2 = *(const bf16x8*)&Wt1[(2 * 16 + m) * IN_F + kb];
        bf16x8 b3 = *(const bf16x8*)&Wt1[(3 * 16 + m) * IN_F + kb];
        acc0 = __builtin_amdgcn_mfma_f32_16x16x32_bf16(A.v, b0, acc0, 0, 0, 0);
        acc1 = __builtin_amdgcn_mfma_f32_16x16x32_bf16(A.v, b1, acc1, 0, 0, 0);
        acc2 = __builtin_amdgcn_mfma_f32_16x16x32_bf16(A.v, b2, acc2, 0, 0, 0);
        acc3 = __builtin_amdgcn_mfma_f32_16x16x32_bf16(A.v, b3, acc3, 0, 0, 0);
    }
    int rbase = w * 16 + quad * 4;
#pragma unroll
    for (int reg = 0; reg < 4; reg++) {
        int r = rbase + reg;
        float d = dv[r];
        Cs[r * 72 +  0 + m] = f2bf(acc0[reg] * d);
        Cs[r * 72 + 16 + m] = f2bf(acc1[reg] * d);
        Cs[r * 72 + 32 + m] = f2bf(acc2[reg] * d);
        Cs[r * 72 + 48 + m] = f2bf(acc3[reg] * d);
    }
    __syncthreads();
#pragma unroll
    for (int it = 0; it < 4; it++) {
        int idx = it * 256 + tid;
        int r = idx >> 4, c = idx & 15;
        int nd = node0 + r;
        if (nd < N_NODES) {
            uint2 vv = *(const uint2*)&Cs[r * 72 + c * 4];
            *(uint2*)&t1[(size_t)nd * HID_F + c * 4] = vv;
        }
    }
}

// ---------------- FUSED agg1+gemm2: h1 lives in LDS only; emits t2s --------------
// Phase A (agg1): quarter-wave = node, lane fl holds feats 4fl..4fl+3.
// Phase B (gemm2): MFMA h1s @ Wt2 -> t2s = bf16(dinv * (h1@W2)).
__global__ __launch_bounds__(256) void agg1gemm2_kernel(const unsigned short* __restrict__ t1,
                                                        const int* __restrict__ rowptr,
                                                        const int* __restrict__ col,
                                                        const float* __restrict__ dinv,
                                                        const float* __restrict__ b1,
                                                        const unsigned short* __restrict__ Wt2,
                                                        unsigned short* __restrict__ t2s) {
    __shared__ int lcol[AGG_CAP];
    __shared__ int lrp[65];
    __shared__ float ldv[64];
    __shared__ unsigned short h1s[64 * 72];   // bf16 h1 tile, row stride 72 shorts
    __shared__ unsigned short Cs[64 * 36];    // t2s staging
    int tid = threadIdx.x;
    int node0 = blockIdx.x * 64;
    if (tid < 65) lrp[tid] = rowptr[min(node0 + tid, N_NODES)];
    __syncthreads();
    int s0 = lrp[0];
    int cnt = lrp[64] - s0; if (cnt > AGG_CAP) cnt = AGG_CAP;
    for (int k = tid; k < cnt; k += 256) lcol[k] = col[s0 + k];
    if (tid < 64) {
        int n = node0 + tid;
        ldv[tid] = (n < N_NODES) ? dinv[n] : 0.f;
    }
    __syncthreads();
    int lane = tid & 63, w = tid >> 6;
    int q = lane >> 4, fl = lane & 15;
    int qg = w * 4 + q;                    // 0..15
    const uint2* t1v = (const uint2*)t1;   // row stride 16 uint2
    float4 bb = ((const float4*)b1)[fl];
#pragma unroll
    for (int rep = 0; rep < 4; rep++) {
        int li = qg + rep * 16;
        int node = node0 + li;
        uint2 pk = make_uint2(0u, 0u);
        if (node < N_NODES) {
            int s = lrp[li] - s0;
            int e = lrp[li + 1] - s0; if (e > cnt) e = cnt;
            float a0 = 0.f, a1 = 0.f, a2 = 0.f, a3 = 0.f;
            int p = s;
            for (; p + 3 < e; p += 4) {
                int c0 = lcol[p], c1 = lcol[p + 1], c2 = lcol[p + 2], c3 = lcol[p + 3];
                uint2 u0 = t1v[(size_t)c0 * 16 + fl];
                uint2 u1 = t1v[(size_t)c1 * 16 + fl];
                uint2 u2 = t1v[(size_t)c2 * 16 + fl];
                uint2 u3 = t1v[(size_t)c3 * 16 + fl];
                a0 += bflo(u0.x) + bflo(u1.x) + bflo(u2.x) + bflo(u3.x);
                a1 += bfhi(u0.x) + bfhi(u1.x) + bfhi(u2.x) + bfhi(u3.x);
                a2 += bflo(u0.y) + bflo(u1.y) + bflo(u2.y) + bflo(u3.y);
                a3 += bfhi(u0.y) + bfhi(u1.y) + bfhi(u2.y) + bfhi(u3.y);
            }
            for (; p < e; p++) {
                uint2 u = t1v[(size_t)lcol[p] * 16 + fl];
                a0 += bflo(u.x); a1 += bfhi(u.x);
                a2 += bflo(u.y); a3 += bfhi(u.y);
            }
            uint2 us = t1v[(size_t)node * 16 + fl];   // self (already dinv-scaled)
            float di = ldv[li];
            float o0 = fmaxf(di * (a0 + bflo(us.x)) + bb.x, 0.f);
            float o1 = fmaxf(di * (a1 + bfhi(us.x)) + bb.y, 0.f);
            float o2 = fmaxf(di * (a2 + bflo(us.y)) + bb.z, 0.f);
            float o3 = fmaxf(di * (a3 + bfhi(us.y)) + bb.w, 0.f);
            pk.x = pack2bf(o0, o1);
            pk.y = pack2bf(o2, o3);
        }
        *(uint2*)&h1s[li * 72 + fl * 4] = pk;
    }
    __syncthreads();
    // ---- gemm2 MFMA: K=64 (2 steps), N=32 (2 tiles) ----
    int m = lane & 15, quad = lane >> 4;
    int row = w * 16 + m;
    f32x4 acc0 = {0.f, 0.f, 0.f, 0.f};
    f32x4 acc1 = acc0;
#pragma unroll
    for (int ks = 0; ks < 2; ks++) {
        int kb = ks * 32 + quad * 8;
        bf16x8 a  = *(const bf16x8*)&h1s[row * 72 + kb];
        bf16x8 b0 = *(const bf16x8*)&Wt2[(0 * 16 + m) * HID_F + kb];
        bf16x8 b1 = *(const bf16x8*)&Wt2[(1 * 16 + m) * HID_F + kb];
        acc0 = __builtin_amdgcn_mfma_f32_16x16x32_bf16(a, b0, acc0, 0, 0, 0);
        acc1 = __builtin_amdgcn_mfma_f32_16x16x32_bf16(a, b1, acc1, 0, 0, 0);
    }
    int rbase = w * 16 + quad * 4;
#pragma unroll
    for (int reg = 0; reg < 4; reg++) {
        int r = rbase + reg;
        float d = ldv[r];
        Cs[r * 36 +  0 + m] = f2bf(acc0[reg] * d);
        Cs[r * 36 + 16 + m] = f2bf(acc1[reg] * d);
    }
    __syncthreads();
#pragma unroll
    for (int it = 0; it < 2; it++) {
        int idx = it * 256 + tid;
        int r = idx >> 3, c = idx & 7;
        int nd = node0 + r;
        if (nd < N_NODES) {
            uint2 vv = *(const uint2*)&Cs[r * 36 + c * 4];
            *(uint2*)&t2s[(size_t)nd * Z_F + c * 4] = vv;
        }
    }
}

// ---------------- FUSED agg2+heads: h2 lives in LDS only; emits out --------------
// Phase A (agg2): octet = node, lane fo holds feats 4fo..4fo+3.
// Phase B (heads): MFMA h2s @ Wth(+bias) -> out [mu|lv].
__global__ __launch_bounds__(256) void agg2heads_kernel(const unsigned short* __restrict__ t2s,
                                                        const int* __restrict__ rowptr,
                                                        const int* __restrict__ col,
                                                        const float* __restrict__ dinv,
                                                        const float* __restrict__ b2,
                                                        const unsigned short* __restrict__ Wth,
                                                        const float* __restrict__ bmu,
                                                        const float* __restrict__ blv,
                                                        float* __restrict__ out) {
    __shared__ int lcol[AGG_CAP];
    __shared__ int lrp[65];
    __shared__ float ldv[64];
    __shared__ unsigned short h2s[64 * 40];   // bf16 h2 tile, row stride 40 shorts
    __shared__ float Cf[64 * 68];             // out staging
    __shared__ float bias[64];
    int tid = threadIdx.x;
    int node0 = blockIdx.x * 64;
    if (tid < 65) lrp[tid] = rowptr[min(node0 + tid, N_NODES)];
    else if (tid >= 96 && tid < 128) bias[tid - 96] = bmu[tid - 96];
    else if (tid >= 128 && tid < 160) bias[tid - 96] = blv[tid - 128];
    __syncthreads();
    int s0 = lrp[0];
    int cnt = lrp[64] - s0; if (cnt > AGG_CAP) cnt = AGG_CAP;
    for (int k = tid; k < cnt; k += 256) lcol[k] = col[s0 + k];
    if (tid < 64) {
        int n = node0 + tid;
        ldv[tid] = (n < N_NODES) ? dinv[n] : 0.f;
    }
    __syncthreads();
    int lane = tid & 63, w = tid >> 6;
    int oc = lane >> 3, fo = lane & 7;
    int og = w * 8 + oc;                   // 0..31
    const uint2* t2v = (const uint2*)t2s;  // row stride 8 uint2
    float4 bb = ((const float4*)b2)[fo];
#pragma unroll
    for (int rep = 0; rep < 2; rep++) {
        int li = og + rep * 32;
        int node = node0 + li;
        uint2 pk = make_uint2(0u, 0u);
        if (node < N_NODES) {
            int s = lrp[li] - s0;
            int e = lrp[li + 1] - s0; if (e > cnt) e = cnt;
            float a0 = 0.f, a1 = 0.f, a2 = 0.f, a3 = 0.f;
            int p = s;
            for (; p + 3 < e; p += 4) {
                int c0 = lcol[p], c1 = lcol[p + 1], c2 = lcol[p + 2], c3 = lcol[p + 3];
                uint2 u0 = t2v[(size_t)c0 * 8 + fo];
                uint2 u1 = t2v[(size_t)c1 * 8 + fo];
                uint2 u2 = t2v[(size_t)c2 * 8 + fo];
                uint2 u3 = t2v[(size_t)c3 * 8 + fo];
                a0 += bflo(u0.x) + bflo(u1.x) + bflo(u2.x) + bflo(u3.x);
                a1 += bfhi(u0.x) + bfhi(u1.x) + bfhi(u2.x) + bfhi(u3.x);
                a2 += bflo(u0.y) + bflo(u1.y) + bflo(u2.y) + bflo(u3.y);
                a3 += bfhi(u0.y) + bfhi(u1.y) + bfhi(u2.y) + bfhi(u3.y);
            }
            for (; p < e; p++) {
                uint2 u = t2v[(size_t)lcol[p] * 8 + fo];
                a0 += bflo(u.x); a1 += bfhi(u.x);
                a2 += bflo(u.y); a3 += bfhi(u.y);
            }
            uint2 us = t2v[(size_t)node * 8 + fo];
            float di = ldv[li];
            float o0 = di * (a0 + bflo(us.x)) + bb.x;
            float o1 = di * (a1 + bfhi(us.x)) + bb.y;
            float o2 = di * (a2 + bflo(us.y)) + bb.z;
            float o3 = di * (a3 + bfhi(us.y)) + bb.w;
            pk.x = pack2bf(o0, o1);
            pk.y = pack2bf(o2, o3);
        }
        *(uint2*)&h2s[li * 40 + fo * 4] = pk;
    }
    __syncthreads();
    // ---- heads MFMA: K=32 (1 step), N=64 (4 tiles: mu 0-31, lv 32-63) ----
    int m = lane & 15, quad = lane >> 4;
    int row = w * 16 + m;
    int kb = quad * 8;
    bf16x8 a  = *(const bf16x8*)&h2s[row * 40 + kb];
    bf16x8 b0 = *(const bf16x8*)&Wth[(0 * 16 + m) * Z_F + kb];
    bf16x8 b1 = *(const bf16x8*)&Wth[(1 * 16 + m) * Z_F + kb];
    bf16x8 b2v = *(const bf16x8*)&Wth[(2 * 16 + m) * Z_F + kb];
    bf16x8 b3 = *(const bf16x8*)&Wth[(3 * 16 + m) * Z_F + kb];
    f32x4 acc0 = {0.f, 0.f, 0.f, 0.f};
    f32x4 acc1 = acc0, acc2 = acc0, acc3 = acc0;
    acc0 = __builtin_amdgcn_mfma_f32_16x16x32_bf16(a, b0, acc0, 0, 0, 0);
    acc1 = __builtin_amdgcn_mfma_f32_16x16x32_bf16(a, b1, acc1, 0, 0, 0);
    acc2 = __builtin_amdgcn_mfma_f32_16x16x32_bf16(a, b2v, acc2, 0, 0, 0);
    acc3 = __builtin_amdgcn_mfma_f32_16x16x32_bf16(a, b3, acc3, 0, 0, 0);
    int rbase = w * 16 + quad * 4;
#pragma unroll
    for (int reg = 0; reg < 4; reg++) {
        int r = rbase + reg;
        Cf[r * 68 +  0 + m] = acc0[reg] + bias[ 0 + m];
        Cf[r * 68 + 16 + m] = acc1[reg] + bias[16 + m];
        Cf[r * 68 + 32 + m] = acc2[reg] + bias[32 + m];
        Cf[r * 68 + 48 + m] = acc3[reg] + bias[48 + m];
    }
    __syncthreads();
#pragma unroll
    for (int it = 0; it < 2; it++) {
        int idx = it * 256 + tid;
        int r = idx >> 3, c = idx & 7;
        int nd = node0 + r;
        if (nd < N_NODES) {
            float4 vmu = *(const float4*)&Cf[r * 68 + c * 4];
            float4 vlv = *(const float4*)&Cf[r * 68 + 32 + c * 4];
            *(float4*)&out[(size_t)nd * Z_F + c * 4] = vmu;
            *(float4*)&out[(size_t)N_NODES * Z_F + (size_t)nd * Z_F + c * 4] = vlv;
        }
    }
}

extern "C" void kernel_launch(void* const* d_in, const int* in_sizes, int n_in,
                              void* d_out, int out_size, void* d_ws, size_t ws_size,
                              hipStream_t stream) {
    const float* x   = (const float*)d_in[0];
    const int*   ei  = (const int*)d_in[1];
    const float* W1  = (const float*)d_in[2];
    const float* b1  = (const float*)d_in[3];
    const float* W2  = (const float*)d_in[4];
    const float* b2  = (const float*)d_in[5];
    const float* Wmu = (const float*)d_in[6];
    const float* bmu = (const float*)d_in[7];
    const float* Wlv = (const float*)d_in[8];
    const float* blv = (const float*)d_in[9];
    float* out = (float*)d_out;

    char* ws = (char*)d_ws;
    size_t off = 0;
    auto A = [&](size_t bytes) {
        size_t r = off;
        off += (bytes + 255) & ~(size_t)255;
        return r;
    };
    int*   gcur       = (int*)(ws + A((size_t)NBUK * 4));
    int*   bucketBase = (int*)(ws + A((size_t)NBUK * 4));
    int*   rowptr     = (int*)(ws + A((size_t)(N_NODES + 1) * 4));
    float* dinv       = (float*)(ws + A((size_t)N_NODES * 4));
    unsigned short* Wt1 = (unsigned short*)(ws + A((size_t)IN_F * HID_F * 2));
    unsigned short* Wt2 = (unsigned short*)(ws + A((size_t)HID_F * Z_F * 2));
    unsigned short* Wth = (unsigned short*)(ws + A((size_t)Z_F * 64 * 2));
    int*   col        = (int*)(ws + A((size_t)N_EDGES * 4));                    // 6.4 MB
    char*  reg1 = ws + A((size_t)NBUK * BCAP * 4);                              // 9.6 MB: pairs -> t2s
    uint32* pairs = (uint32*)reg1;                // dead after phase2
    unsigned short* t2s = (unsigned short*)reg1;  // 6.4 MB, written by agg1gemm2
    unsigned short* t1 = (unsigned short*)(ws + A((size_t)N_NODES * HID_F * 2)); // 12.8 MB

    hipMemsetAsync(gcur, 0, (size_t)NBUK * 4, stream);

    phase1_kernel<<<P1_BLOCKS, 256, 0, stream>>>(ei, gcur, pairs);
    prep_kernel<<<1, 1024, 0, stream>>>(gcur, W1, W2, Wmu, Wlv, bucketBase, rowptr,
                                        Wt1, Wt2, Wth);
    phase2_kernel<<<NBUK, 256, 0, stream>>>(pairs, gcur, bucketBase, rowptr, dinv, col);

    int nblk = (N_NODES + 63) / 64;   // 1563
    gemm1_kernel<<<nblk, 256, 0, stream>>>(x, Wt1, dinv, t1);
    agg1gemm2_kernel<<<nblk, 256, 0, stream>>>(t1, rowptr, col, dinv, b1, Wt2, t2s);
    agg2heads_kernel<<<nblk, 256, 0, stream>>>(t2s, rowptr, col, dinv, b2, Wth, bmu, blv, out);
}